// Round 2
// baseline (4658.303 us; speedup 1.0000x reference)
//
#include <hip/hip_runtime.h>
#include <math.h>

#define N_ROWS 16384
#define M_ANCH 8192
#define DDIM   512
#define FDIM   2048
#define KNN    5
#define BN_EPS 1e-5f
#define CHUNK  8192   // encoder row-chunk: hidden buffer = CHUNK*FDIM*4 = 64 MB

// Workspace budget (floats): norm_a 8192 + sums 3072 + bufA N*D (8,388,608)
//   + bufC CHUNK*FDIM (16,777,216)  = 25,177,088 floats = 96.05 MB.
// d_out (32 MB) doubles as the `comb` intermediate (dead before final write).

__device__ __forceinline__ bool kless(float k1, int i1, float k2, int i2) {
    return (k1 < k2) || (k1 == k2 && i1 < i2);
}

// insert (key,id) into ascending sorted top-5 (bk[0] best). Static indices only.
__device__ __forceinline__ void insert5(float (&bk)[KNN], int (&bi)[KNN], float key, int id) {
    if (!kless(key, id, bk[4], bi[4])) return;
    bool c3 = kless(key, id, bk[3], bi[3]);
    bool c2 = kless(key, id, bk[2], bi[2]);
    bool c1 = kless(key, id, bk[1], bi[1]);
    bool c0 = kless(key, id, bk[0], bi[0]);
    bk[4] = c3 ? bk[3] : key;                  bi[4] = c3 ? bi[3] : id;
    bk[3] = c3 ? (c2 ? bk[2] : key) : bk[3];   bi[3] = c3 ? (c2 ? bi[2] : id) : bi[3];
    bk[2] = c2 ? (c1 ? bk[1] : key) : bk[2];   bi[2] = c2 ? (c1 ? bi[1] : id) : bi[2];
    bk[1] = c1 ? (c0 ? bk[0] : key) : bk[1];   bi[1] = c1 ? (c0 ? bi[0] : id) : bi[1];
    bk[0] = c0 ? key : bk[0];                  bi[0] = c0 ? id : bi[0];
}

__global__ void zero_kernel(float* p, int n) {
    int i = blockIdx.x * blockDim.x + threadIdx.x;
    if (i < n) p[i] = 0.f;
}

// norm_a[m] = sum_d anchor[m][d]^2 ; one wave per row
__global__ __launch_bounds__(256) void anchor_norm_kernel(const float* __restrict__ a,
                                                          float* __restrict__ norm_a) {
    int wave = threadIdx.x >> 6, lane = threadIdx.x & 63;
    int row = blockIdx.x * 4 + wave;
    const float4* ar = (const float4*)(a + (size_t)row * DDIM);
    float4 v1 = ar[lane * 2];
    float4 v2 = ar[lane * 2 + 1];
    float s = v1.x*v1.x + v1.y*v1.y + v1.z*v1.z + v1.w*v1.w
            + v2.x*v2.x + v2.y*v2.y + v2.z*v2.z + v2.w*v2.w;
    for (int off = 32; off; off >>= 1) s += __shfl_xor(s, off, 64);
    if (lane == 0) norm_a[row] = s;
}

// Fused: dist (ranking key = ||a||^2 - 2 s.a) + per-row top-5 + gather-mean -> neigh
// 512 threads, 64 src rows/block. LDS ~43 KB.
__global__ __launch_bounds__(512) void dist_topk_kernel(
    const float* __restrict__ src, const float* __restrict__ anchor,
    const float* __restrict__ norm_a, float* __restrict__ neigh)
{
    __shared__ float As[64][128];     // src K-quarter tile
    __shared__ float Bs[8][256];      // anchor k-slab (transposed)
    __shared__ float norm_s[256];
    __shared__ int   idx_s[64][KNN];

    const int t = threadIdx.x;
    const int row0 = blockIdx.x * 64;
    const int ty = t >> 5;   // 0..15 -> rows ty*4..ty*4+3
    const int tx = t & 31;   // anchor groups

    float bk[4][KNN]; int bi[4][KNN];
    #pragma unroll
    for (int i = 0; i < 4; ++i)
        #pragma unroll
        for (int q = 0; q < KNN; ++q) { bk[i][q] = 3.0e38f; bi[i][q] = 0x7fffffff; }

    for (int m0 = 0; m0 < M_ANCH; m0 += 256) {
        __syncthreads();
        if (t < 256) norm_s[t] = norm_a[m0 + t];
        float acc[4][8];
        #pragma unroll
        for (int i = 0; i < 4; ++i)
            #pragma unroll
            for (int j = 0; j < 8; ++j) acc[i][j] = 0.f;

        for (int kq = 0; kq < 4; ++kq) {
            const int kbase = kq * 128;
            __syncthreads();
            // stage src quarter: 64 rows x 128 k
            #pragma unroll
            for (int it = 0; it < 4; ++it) {
                int g = it * 512 + t;
                int r = g >> 5, kg = g & 31;
                float4 v = *(const float4*)(src + (size_t)(row0 + r) * DDIM + kbase + kg * 4);
                *(float4*)&As[r][kg * 4] = v;
            }
            for (int k0 = 0; k0 < 128; k0 += 8) {
                __syncthreads();
                {
                    int m = t & 255, kh = t >> 8;
                    float4 v = *(const float4*)(anchor + (size_t)(m0 + m) * DDIM + kbase + k0 + kh * 4);
                    Bs[kh*4+0][m] = v.x; Bs[kh*4+1][m] = v.y;
                    Bs[kh*4+2][m] = v.z; Bs[kh*4+3][m] = v.w;
                }
                __syncthreads();
                #pragma unroll
                for (int k = 0; k < 8; ++k) {
                    float b[8];
                    *(float4*)&b[0] = *(const float4*)&Bs[k][tx * 4];
                    *(float4*)&b[4] = *(const float4*)&Bs[k][128 + tx * 4];
                    #pragma unroll
                    for (int i = 0; i < 4; ++i) {
                        float s = As[ty * 4 + i][k0 + k];
                        #pragma unroll
                        for (int j = 0; j < 8; ++j) acc[i][j] += s * b[j];
                    }
                }
            }
        }
        // top-5 update (key ordering == d2 ordering; ||s||^2 is row-constant)
        #pragma unroll
        for (int i = 0; i < 4; ++i) {
            #pragma unroll
            for (int j = 0; j < 8; ++j) {
                int ml = (j < 4) ? (tx * 4 + j) : (128 + tx * 4 + (j - 4));
                float key = norm_s[ml] - 2.f * acc[i][j];
                int id = m0 + ml;
                if (kless(key, id, bk[i][4], bi[i][4])) insert5(bk[i], bi[i], key, id);
            }
        }
    }

    // butterfly merge across the 32 threads (same ty) sharing rows
    for (int off = 16; off >= 1; off >>= 1) {
        #pragma unroll
        for (int i = 0; i < 4; ++i) {
            float ok[KNN]; int oi[KNN];
            #pragma unroll
            for (int q = 0; q < KNN; ++q) {
                ok[q] = __shfl_xor(bk[i][q], off, 64);
                oi[q] = __shfl_xor(bi[i][q], off, 64);
            }
            #pragma unroll
            for (int q = 0; q < KNN; ++q) insert5(bk[i], bi[i], ok[q], oi[q]);
        }
    }
    if (tx == 0) {
        #pragma unroll
        for (int i = 0; i < 4; ++i)
            #pragma unroll
            for (int q = 0; q < KNN; ++q) idx_s[ty * 4 + i][q] = bi[i][q];
    }
    __syncthreads();
    // gather-mean: neigh[row] = mean of 5 anchor rows
    {
        int r = t >> 3, dg = t & 7;
        int i0 = idx_s[r][0], i1 = idx_s[r][1], i2 = idx_s[r][2], i3 = idx_s[r][3], i4 = idx_s[r][4];
        const float4* a0 = (const float4*)(anchor + (size_t)i0 * DDIM);
        const float4* a1 = (const float4*)(anchor + (size_t)i1 * DDIM);
        const float4* a2 = (const float4*)(anchor + (size_t)i2 * DDIM);
        const float4* a3 = (const float4*)(anchor + (size_t)i3 * DDIM);
        const float4* a4 = (const float4*)(anchor + (size_t)i4 * DDIM);
        float4* np = (float4*)(neigh + (size_t)(row0 + r) * DDIM);
        #pragma unroll
        for (int dd = 0; dd < 16; ++dd) {
            int d4 = dg * 16 + dd;
            float4 v0 = a0[d4], v1 = a1[d4], v2 = a2[d4], v3 = a3[d4], v4 = a4[d4];
            float4 o;
            o.x = (v0.x + v1.x + v2.x + v3.x + v4.x) * 0.2f;
            o.y = (v0.y + v1.y + v2.y + v3.y + v4.y) * 0.2f;
            o.z = (v0.z + v1.z + v2.z + v3.z + v4.z) * 0.2f;
            o.w = (v0.w + v1.w + v2.w + v3.w + v4.w) * 0.2f;
            np[d4] = o;
        }
    }
}

// Generic fp32 GEMM: C = act([A|A2] @ B + bias). 128x128 tile, BK=16, 8x8 micro.
template<int ACT>
__global__ __launch_bounds__(256) void gemm_kernel(
    const float* __restrict__ A, int K1,
    const float* __restrict__ A2, int K2,
    const float* __restrict__ B, const float* __restrict__ bias,
    float* __restrict__ C, int Ncols)
{
    __shared__ float As[16][132];   // [k][row], padded
    __shared__ float Bs[16][128];
    const int t = threadIdx.x;
    const int n0 = blockIdx.x * 128;
    const int m0 = blockIdx.y * 128;
    const int ty = t >> 4, tx = t & 15;
    const int K = K1 + K2;

    float acc[8][8];
    #pragma unroll
    for (int i = 0; i < 8; ++i)
        #pragma unroll
        for (int j = 0; j < 8; ++j) acc[i][j] = 0.f;

    const int ar = t >> 1;          // 0..127
    const int akc = (t & 1) * 8;    // 0 or 8
    const int bkr = t >> 4;         // 0..15
    const int bc = (t & 15) * 8;    // 0..120

    for (int k0 = 0; k0 < K; k0 += 16) {
        int kk = k0 + akc;
        float4 v0, v1;
        if (kk < K1) {
            const float* p = A + (size_t)(m0 + ar) * K1 + kk;
            v0 = *(const float4*)p; v1 = *(const float4*)(p + 4);
        } else {
            const float* p = A2 + (size_t)(m0 + ar) * K2 + (kk - K1);
            v0 = *(const float4*)p; v1 = *(const float4*)(p + 4);
        }
        const float* bp = B + (size_t)(k0 + bkr) * Ncols + n0 + bc;
        float4 w0 = *(const float4*)bp, w1 = *(const float4*)(bp + 4);
        __syncthreads();
        As[akc+0][ar] = v0.x; As[akc+1][ar] = v0.y; As[akc+2][ar] = v0.z; As[akc+3][ar] = v0.w;
        As[akc+4][ar] = v1.x; As[akc+5][ar] = v1.y; As[akc+6][ar] = v1.z; As[akc+7][ar] = v1.w;
        *(float4*)&Bs[bkr][bc] = w0; *(float4*)&Bs[bkr][bc + 4] = w1;
        __syncthreads();
        #pragma unroll
        for (int k = 0; k < 16; ++k) {
            float a[8], b[8];
            *(float4*)&a[0] = *(const float4*)&As[k][ty * 8];
            *(float4*)&a[4] = *(const float4*)&As[k][ty * 8 + 4];
            *(float4*)&b[0] = *(const float4*)&Bs[k][tx * 4];
            *(float4*)&b[4] = *(const float4*)&Bs[k][64 + tx * 4];
            #pragma unroll
            for (int i = 0; i < 8; ++i)
                #pragma unroll
                for (int j = 0; j < 8; ++j) acc[i][j] += a[i] * b[j];
        }
    }
    float4 bv0 = *(const float4*)(bias + n0 + tx * 4);
    float4 bv1 = *(const float4*)(bias + n0 + 64 + tx * 4);
    #pragma unroll
    for (int i = 0; i < 8; ++i) {
        int row = m0 + ty * 8 + i;
        float4 o0, o1;
        o0.x = acc[i][0] + bv0.x; o0.y = acc[i][1] + bv0.y;
        o0.z = acc[i][2] + bv0.z; o0.w = acc[i][3] + bv0.w;
        o1.x = acc[i][4] + bv1.x; o1.y = acc[i][5] + bv1.y;
        o1.z = acc[i][6] + bv1.z; o1.w = acc[i][7] + bv1.w;
        if (ACT == 1) {
            o0.x = tanhf(o0.x); o0.y = tanhf(o0.y); o0.z = tanhf(o0.z); o0.w = tanhf(o0.w);
            o1.x = tanhf(o1.x); o1.y = tanhf(o1.y); o1.z = tanhf(o1.z); o1.w = tanhf(o1.w);
        }
        *(float4*)(C + (size_t)row * Ncols + n0 + tx * 4) = o0;
        *(float4*)(C + (size_t)row * Ncols + n0 + 64 + tx * 4) = o1;
    }
}

// BN stats: partial sums + atomics. sums[0:512]=sum, sums[512:1024]=sumsq
__global__ __launch_bounds__(256) void bn_stats_kernel(const float* __restrict__ X,
                                                       float* __restrict__ sums)
{
    __shared__ float red[8][64];
    int lane = threadIdx.x & 63;
    int rl = threadIdx.x >> 6;
    int c = blockIdx.x * 64 + lane;
    int chunk = N_ROWS / gridDim.y;
    int rbeg = blockIdx.y * chunk;
    float s = 0.f, s2 = 0.f;
    for (int r = rbeg + rl; r < rbeg + chunk; r += 4) {
        float v = X[(size_t)r * DDIM + c];
        s += v; s2 += v * v;
    }
    red[rl][lane] = s; red[4 + rl][lane] = s2;
    __syncthreads();
    if (threadIdx.x < 64) {
        float ts = red[0][lane] + red[1][lane] + red[2][lane] + red[3][lane];
        float t2 = red[4][lane] + red[5][lane] + red[6][lane] + red[7][lane];
        atomicAdd(&sums[c], ts);
        atomicAdd(&sums[DDIM + c], t2);
    }
}

template<int TANH>
__global__ __launch_bounds__(256) void bn_apply_kernel(
    const float* __restrict__ X, float* __restrict__ Y,
    const float* __restrict__ sums, const float* __restrict__ g,
    const float* __restrict__ b, float invN)
{
    size_t i = (size_t)blockIdx.x * 256 + threadIdx.x;  // float4 index over N*D/4
    int cg = (int)(i % (DDIM / 4));
    int c = cg * 4;
    float4 x = ((const float4*)X)[i];
    float4 sm = *(const float4*)(sums + c);
    float4 sq = *(const float4*)(sums + DDIM + c);
    float4 gv = *(const float4*)(g + c);
    float4 bv = *(const float4*)(b + c);
    float m, var, rs;
    m = sm.x * invN; var = sq.x * invN - m * m; rs = rsqrtf(var + BN_EPS);
    x.x = (x.x - m) * rs * gv.x + bv.x;
    m = sm.y * invN; var = sq.y * invN - m * m; rs = rsqrtf(var + BN_EPS);
    x.y = (x.y - m) * rs * gv.y + bv.y;
    m = sm.z * invN; var = sq.z * invN - m * m; rs = rsqrtf(var + BN_EPS);
    x.z = (x.z - m) * rs * gv.z + bv.z;
    m = sm.w * invN; var = sq.w * invN - m * m; rs = rsqrtf(var + BN_EPS);
    x.w = (x.w - m) * rs * gv.w + bv.w;
    if (TANH) { x.x = tanhf(x.x); x.y = tanhf(x.y); x.z = tanhf(x.z); x.w = tanhf(x.w); }
    ((float4*)Y)[i] = x;
}

__global__ __launch_bounds__(256) void add_kernel(float* __restrict__ dst,
                                                  const float* __restrict__ src)
{
    size_t i = (size_t)blockIdx.x * 256 + threadIdx.x;
    float4 a = ((const float4*)dst)[i];
    float4 b = ((const float4*)src)[i];
    a.x += b.x; a.y += b.y; a.z += b.z; a.w += b.w;
    ((float4*)dst)[i] = a;
}

extern "C" void kernel_launch(void* const* d_in, const int* in_sizes, int n_in,
                              void* d_out, int out_size, void* d_ws, size_t ws_size,
                              hipStream_t stream)
{
    const float* src   = (const float*)d_in[0];
    const float* anc   = (const float*)d_in[1];
    const float* W_dim = (const float*)d_in[2];
    const float* b_dim = (const float*)d_in[3];
    const float* W_fus = (const float*)d_in[4];
    const float* b_fus = (const float*)d_in[5];
    const float* W_e1  = (const float*)d_in[6];
    const float* b_e1  = (const float*)d_in[7];
    const float* W_e2  = (const float*)d_in[8];
    const float* b_e2  = (const float*)d_in[9];
    const float* g1    = (const float*)d_in[10];
    const float* bt1   = (const float*)d_in[11];
    const float* g2    = (const float*)d_in[12];
    const float* bt2   = (const float*)d_in[13];
    const float* W_d   = (const float*)d_in[14];
    const float* b_d   = (const float*)d_in[15];
    const float* g_d   = (const float*)d_in[16];
    const float* bt_d  = (const float*)d_in[17];
    float* out = (float*)d_out;          // reused as `comb` intermediate

    float* ws = (float*)d_ws;
    const size_t ND = (size_t)N_ROWS * DDIM;
    float* norm_a = ws;                  // 8192
    float* sums1  = ws + 8192;           // 1024
    float* sums2  = sums1 + 1024;        // 1024
    float* sums3  = sums2 + 1024;        // 1024
    float* bufA   = ws + 8192 + 3072;    // N*D: neigh, later enc2-out (t+comb)
    float* bufC   = bufA + ND;           // CHUNK*FDIM: a_map chunk, later h chunk

    const float invN = 1.0f / (float)N_ROWS;

    zero_kernel<<<dim3(12), 256, 0, stream>>>(sums1, 3072);
    anchor_norm_kernel<<<dim3(M_ANCH / 4), 256, 0, stream>>>(anc, norm_a);
    dist_topk_kernel<<<dim3(N_ROWS / 64), 512, 0, stream>>>(src, anc, norm_a, bufA);

    // Phase 1 (chunked): a_map chunk + fused-concat -> comb (stored in d_out)
    for (int r0 = 0; r0 < N_ROWS; r0 += CHUNK) {
        gemm_kernel<0><<<dim3(DDIM / 128, CHUNK / 128), 256, 0, stream>>>(
            bufA + (size_t)r0 * DDIM, DDIM, nullptr, 0, W_dim, b_dim, bufC, DDIM);
        gemm_kernel<0><<<dim3(DDIM / 128, CHUNK / 128), 256, 0, stream>>>(
            src + (size_t)r0 * DDIM, DDIM, bufC, DDIM, W_fus, b_fus,
            out + (size_t)r0 * DDIM, DDIM);
    }
    // BN1 in-place on comb (= out)
    bn_stats_kernel<<<dim3(DDIM / 64, 16), 256, 0, stream>>>(out, sums1);
    bn_apply_kernel<0><<<dim3(8192), 256, 0, stream>>>(out, out, sums1, g1, bt1, invN);

    // Phase 2 (chunked): h = tanh(comb@W_e1+b1) -> bufC ; t = h@W_e2+b2 -> bufA
    for (int r0 = 0; r0 < N_ROWS; r0 += CHUNK) {
        gemm_kernel<1><<<dim3(FDIM / 128, CHUNK / 128), 256, 0, stream>>>(
            out + (size_t)r0 * DDIM, DDIM, nullptr, 0, W_e1, b_e1, bufC, FDIM);
        gemm_kernel<0><<<dim3(DDIM / 128, CHUNK / 128), 256, 0, stream>>>(
            bufC, FDIM, nullptr, 0, W_e2, b_e2, bufA + (size_t)r0 * DDIM, DDIM);
    }
    // residual + BN2 in-place on bufA
    add_kernel<<<dim3(8192), 256, 0, stream>>>(bufA, out);
    bn_stats_kernel<<<dim3(DDIM / 64, 16), 256, 0, stream>>>(bufA, sums2);
    bn_apply_kernel<0><<<dim3(8192), 256, 0, stream>>>(bufA, bufA, sums2, g2, bt2, invN);

    // decoder: pre-act -> out (comb is dead), BN3 + tanh in-place
    gemm_kernel<0><<<dim3(DDIM / 128, N_ROWS / 128), 256, 0, stream>>>(
        bufA, DDIM, nullptr, 0, W_d, b_d, out, DDIM);
    bn_stats_kernel<<<dim3(DDIM / 64, 16), 256, 0, stream>>>(out, sums3);
    bn_apply_kernel<1><<<dim3(8192), 256, 0, stream>>>(out, out, sums3, g_d, bt_d, invN);
}

// Round 3
// 3995.835 us; speedup vs baseline: 1.1658x; 1.1658x over previous
//
#include <hip/hip_runtime.h>
#include <math.h>

#define N_ROWS 16384
#define M_ANCH 8192
#define DDIM   512
#define FDIM   2048
#define KNN    5
#define BN_EPS 1e-5f
#define CHUNK  8192    // network-phase row chunk (hidden buffer 64 MB)
#define MCHUNK 1024    // dist-phase anchor chunk (score buffer 64 MB)
#define KSPLIT 1536    // 3 x 512 virtual-K for hi/lo split product

typedef _Float16 f16;
typedef _Float16 f16x8 __attribute__((ext_vector_type(8)));
typedef _Float16 f16x4 __attribute__((ext_vector_type(4)));
typedef float f32x4 __attribute__((ext_vector_type(4)));

__device__ __forceinline__ void async_copy16(const void* g, void* l) {
    __builtin_amdgcn_global_load_lds(
        (const __attribute__((address_space(1))) void*)g,
        (__attribute__((address_space(3))) void*)l, 16, 0, 0);
}

__device__ __forceinline__ bool kless(float k1, int i1, float k2, int i2) {
    return (k1 < k2) || (k1 == k2 && i1 < i2);
}

// insert (key,id) into ascending sorted top-5 (bk[0] best).
__device__ __forceinline__ void insert5(float (&bk)[KNN], int (&bi)[KNN], float key, int id) {
    if (!kless(key, id, bk[4], bi[4])) return;
    bool c3 = kless(key, id, bk[3], bi[3]);
    bool c2 = kless(key, id, bk[2], bi[2]);
    bool c1 = kless(key, id, bk[1], bi[1]);
    bool c0 = kless(key, id, bk[0], bi[0]);
    bk[4] = c3 ? bk[3] : key;                  bi[4] = c3 ? bi[3] : id;
    bk[3] = c3 ? (c2 ? bk[2] : key) : bk[3];   bi[3] = c3 ? (c2 ? bi[2] : id) : bi[3];
    bk[2] = c2 ? (c1 ? bk[1] : key) : bk[2];   bi[2] = c2 ? (c1 ? bi[1] : id) : bi[2];
    bk[1] = c1 ? (c0 ? bk[0] : key) : bk[1];   bi[1] = c1 ? (c0 ? bi[0] : id) : bi[1];
    bk[0] = c0 ? key : bk[0];                  bi[0] = c0 ? id : bi[0];
}

__global__ void zero_kernel(float* p, int n) {
    int i = blockIdx.x * blockDim.x + threadIdx.x;
    if (i < n) p[i] = 0.f;
}

__global__ void init_state_kernel(float* bk, int* bi, int n) {
    int i = blockIdx.x * blockDim.x + threadIdx.x;
    if (i < n) { bk[i] = 3.0e38f; bi[i] = 0x7fffffff; }
}

// fp32 -> f16 hi/lo split into virtual-K layout.
// MODE 0 (src): segs [hi | lo | hi];  MODE 1 (anchor): segs [hi | hi | lo]
template<int MODE>
__global__ __launch_bounds__(256) void split_kernel(const float* __restrict__ X,
                                                    f16* __restrict__ Y, int nrows) {
    int i4 = blockIdx.x * 256 + threadIdx.x;           // float4 index
    int row = i4 >> 7;                                  // 128 float4 per row
    int kc = (i4 & 127) * 4;
    if (row >= nrows) return;
    float4 v = ((const float4*)X)[i4];
    f16x4 h, lo;
    h.x = (f16)v.x; h.y = (f16)v.y; h.z = (f16)v.z; h.w = (f16)v.w;
    lo.x = (f16)(v.x - (float)h.x); lo.y = (f16)(v.y - (float)h.y);
    lo.z = (f16)(v.z - (float)h.z); lo.w = (f16)(v.w - (float)h.w);
    f16* base = Y + (size_t)row * KSPLIT + kc;
    if (MODE == 0) {
        *(f16x4*)(base) = h; *(f16x4*)(base + 512) = lo; *(f16x4*)(base + 1024) = h;
    } else {
        *(f16x4*)(base) = h; *(f16x4*)(base + 512) = h;  *(f16x4*)(base + 1024) = lo;
    }
}

// norm_a[m] = sum_d anchor[m][d]^2 ; one wave per row
__global__ __launch_bounds__(256) void anchor_norm_kernel(const float* __restrict__ a,
                                                          float* __restrict__ norm_a) {
    int wave = threadIdx.x >> 6, lane = threadIdx.x & 63;
    int row = blockIdx.x * 4 + wave;
    const float4* ar = (const float4*)(a + (size_t)row * DDIM);
    float4 v1 = ar[lane * 2];
    float4 v2 = ar[lane * 2 + 1];
    float s = v1.x*v1.x + v1.y*v1.y + v1.z*v1.z + v1.w*v1.w
            + v2.x*v2.x + v2.y*v2.y + v2.z*v2.z + v2.w*v2.w;
    for (int off = 32; off; off >>= 1) s += __shfl_xor(s, off, 64);
    if (lane == 0) norm_a[row] = s;
}

// m97-style f16 NT GEMM: C[m][n] = sum_k A[m][k]*B[n][k].  A:[M,K] B:[Nc,K] f16, C fp32.
// 128x128 tile, 256 threads = 4 waves, wave tile 64x64 (4x4 of 16x16x32), BK=32.
__global__ __launch_bounds__(256) void gemm_f16_nt(
    const f16* __restrict__ A, const f16* __restrict__ B,
    float* __restrict__ C, int K, int Ncols)
{
    __shared__ f16 As[128 * 32];
    __shared__ f16 Bs[128 * 32];
    const int t = threadIdx.x;
    const int w = t >> 6, l = t & 63;
    const int m0 = blockIdx.y * 128, n0 = blockIdx.x * 128;
    const int wm = (w & 1) * 64, wn = (w >> 1) * 64;

    f32x4 acc[4][4];
    #pragma unroll
    for (int i = 0; i < 4; ++i)
        #pragma unroll
        for (int j = 0; j < 4; ++j) acc[i][j] = (f32x4){0.f, 0.f, 0.f, 0.f};

    const int srow = l >> 2;          // row within 16-row group
    const int skoff = (l & 3) * 8;    // k offset within 32

    for (int k0 = 0; k0 < K; k0 += 32) {
        __syncthreads();
        #pragma unroll
        for (int s = 0; s < 2; ++s) {
            int grp = w * 2 + s;                  // 0..7 -> rows grp*16..grp*16+15
            int row = grp * 16 + srow;
            async_copy16(A + (size_t)(m0 + row) * K + k0 + skoff, As + grp * 512 + l * 8);
            async_copy16(B + (size_t)(n0 + row) * K + k0 + skoff, Bs + grp * 512 + l * 8);
        }
        __syncthreads();
        f16x8 af[4], bf[4];
        #pragma unroll
        for (int i = 0; i < 4; ++i)
            af[i] = *(const f16x8*)(As + (wm + i * 16 + (l & 15)) * 32 + (l >> 4) * 8);
        #pragma unroll
        for (int j = 0; j < 4; ++j)
            bf[j] = *(const f16x8*)(Bs + (wn + j * 16 + (l & 15)) * 32 + (l >> 4) * 8);
        #pragma unroll
        for (int i = 0; i < 4; ++i)
            #pragma unroll
            for (int j = 0; j < 4; ++j)
                acc[i][j] = __builtin_amdgcn_mfma_f32_16x16x32_f16(af[i], bf[j], acc[i][j], 0, 0, 0);
    }
    #pragma unroll
    for (int i = 0; i < 4; ++i)
        #pragma unroll
        for (int j = 0; j < 4; ++j)
            #pragma unroll
            for (int r = 0; r < 4; ++r) {
                int m = m0 + wm + i * 16 + (l >> 4) * 4 + r;
                int n = n0 + wn + j * 16 + (l & 15);
                C[(size_t)m * Ncols + n] = acc[i][j][r];
            }
}

// top-5 scan over one score chunk; persistent state in ws. One wave per src row.
__global__ __launch_bounds__(256) void topk_scan_kernel(
    const float* __restrict__ g, const float* __restrict__ norm_a,
    float* __restrict__ bk_state, int* __restrict__ bi_state, int m0)
{
    int row = blockIdx.x * 4 + (threadIdx.x >> 6);
    int lane = threadIdx.x & 63;
    float bk[KNN]; int bi[KNN];
    #pragma unroll
    for (int q = 0; q < KNN; ++q) { bk[q] = 3.0e38f; bi[q] = 0x7fffffff; }

    const float* grow = g + (size_t)row * MCHUNK;
    #pragma unroll
    for (int it = 0; it < MCHUNK / 256; ++it) {
        int col = it * 256 + lane * 4;
        float4 gv = *(const float4*)(grow + col);
        float4 nv = *(const float4*)(norm_a + m0 + col);
        insert5(bk, bi, nv.x - 2.f * gv.x, m0 + col);
        insert5(bk, bi, nv.y - 2.f * gv.y, m0 + col + 1);
        insert5(bk, bi, nv.z - 2.f * gv.z, m0 + col + 2);
        insert5(bk, bi, nv.w - 2.f * gv.w, m0 + col + 3);
    }
    for (int off = 32; off >= 1; off >>= 1) {
        float ok[KNN]; int oi[KNN];
        #pragma unroll
        for (int q = 0; q < KNN; ++q) {
            ok[q] = __shfl_xor(bk[q], off, 64);
            oi[q] = __shfl_xor(bi[q], off, 64);
        }
        #pragma unroll
        for (int q = 0; q < KNN; ++q) insert5(bk, bi, ok[q], oi[q]);
    }
    if (lane == 0) {
        #pragma unroll
        for (int q = 0; q < KNN; ++q)
            insert5(bk, bi, bk_state[row * KNN + q], bi_state[row * KNN + q]);
        #pragma unroll
        for (int q = 0; q < KNN; ++q) {
            bk_state[row * KNN + q] = bk[q];
            bi_state[row * KNN + q] = bi[q];
        }
    }
}

// neigh[row] = mean of 5 selected anchor rows. One wave per row.
__global__ __launch_bounds__(256) void gather_mean_kernel(
    const float* __restrict__ anchor, const int* __restrict__ bi_state,
    float* __restrict__ neigh)
{
    int row = blockIdx.x * 4 + (threadIdx.x >> 6);
    int lane = threadIdx.x & 63;
    const int* bi = bi_state + row * KNN;
    int i0 = bi[0], i1 = bi[1], i2 = bi[2], i3 = bi[3], i4 = bi[4];
    const float4* a0 = (const float4*)(anchor + (size_t)i0 * DDIM);
    const float4* a1 = (const float4*)(anchor + (size_t)i1 * DDIM);
    const float4* a2 = (const float4*)(anchor + (size_t)i2 * DDIM);
    const float4* a3 = (const float4*)(anchor + (size_t)i3 * DDIM);
    const float4* a4 = (const float4*)(anchor + (size_t)i4 * DDIM);
    float4* np = (float4*)(neigh + (size_t)row * DDIM);
    #pragma unroll
    for (int p = 0; p < 2; ++p) {
        int c4 = lane + 64 * p;
        float4 v0 = a0[c4], v1 = a1[c4], v2 = a2[c4], v3 = a3[c4], v4 = a4[c4];
        float4 o;
        o.x = (v0.x + v1.x + v2.x + v3.x + v4.x) * 0.2f;
        o.y = (v0.y + v1.y + v2.y + v3.y + v4.y) * 0.2f;
        o.z = (v0.z + v1.z + v2.z + v3.z + v4.z) * 0.2f;
        o.w = (v0.w + v1.w + v2.w + v3.w + v4.w) * 0.2f;
        np[c4] = o;
    }
}

// Generic fp32 GEMM: C = act([A|A2] @ B + bias). 128x128 tile, BK=16, 8x8 micro.
template<int ACT>
__global__ __launch_bounds__(256) void gemm_kernel(
    const float* __restrict__ A, int K1,
    const float* __restrict__ A2, int K2,
    const float* __restrict__ B, const float* __restrict__ bias,
    float* __restrict__ C, int Ncols)
{
    __shared__ float As[16][132];
    __shared__ float Bs[16][128];
    const int t = threadIdx.x;
    const int n0 = blockIdx.x * 128;
    const int m0 = blockIdx.y * 128;
    const int ty = t >> 4, tx = t & 15;
    const int K = K1 + K2;

    float acc[8][8];
    #pragma unroll
    for (int i = 0; i < 8; ++i)
        #pragma unroll
        for (int j = 0; j < 8; ++j) acc[i][j] = 0.f;

    const int ar = t >> 1;
    const int akc = (t & 1) * 8;
    const int bkr = t >> 4;
    const int bc = (t & 15) * 8;

    for (int k0 = 0; k0 < K; k0 += 16) {
        int kk = k0 + akc;
        float4 v0, v1;
        if (kk < K1) {
            const float* p = A + (size_t)(m0 + ar) * K1 + kk;
            v0 = *(const float4*)p; v1 = *(const float4*)(p + 4);
        } else {
            const float* p = A2 + (size_t)(m0 + ar) * K2 + (kk - K1);
            v0 = *(const float4*)p; v1 = *(const float4*)(p + 4);
        }
        const float* bp = B + (size_t)(k0 + bkr) * Ncols + n0 + bc;
        float4 w0 = *(const float4*)bp, w1 = *(const float4*)(bp + 4);
        __syncthreads();
        As[akc+0][ar] = v0.x; As[akc+1][ar] = v0.y; As[akc+2][ar] = v0.z; As[akc+3][ar] = v0.w;
        As[akc+4][ar] = v1.x; As[akc+5][ar] = v1.y; As[akc+6][ar] = v1.z; As[akc+7][ar] = v1.w;
        *(float4*)&Bs[bkr][bc] = w0; *(float4*)&Bs[bkr][bc + 4] = w1;
        __syncthreads();
        #pragma unroll
        for (int k = 0; k < 16; ++k) {
            float a[8], b[8];
            *(float4*)&a[0] = *(const float4*)&As[k][ty * 8];
            *(float4*)&a[4] = *(const float4*)&As[k][ty * 8 + 4];
            *(float4*)&b[0] = *(const float4*)&Bs[k][tx * 4];
            *(float4*)&b[4] = *(const float4*)&Bs[k][64 + tx * 4];
            #pragma unroll
            for (int i = 0; i < 8; ++i)
                #pragma unroll
                for (int j = 0; j < 8; ++j) acc[i][j] += a[i] * b[j];
        }
    }
    float4 bv0 = *(const float4*)(bias + n0 + tx * 4);
    float4 bv1 = *(const float4*)(bias + n0 + 64 + tx * 4);
    #pragma unroll
    for (int i = 0; i < 8; ++i) {
        int row = m0 + ty * 8 + i;
        float4 o0, o1;
        o0.x = acc[i][0] + bv0.x; o0.y = acc[i][1] + bv0.y;
        o0.z = acc[i][2] + bv0.z; o0.w = acc[i][3] + bv0.w;
        o1.x = acc[i][4] + bv1.x; o1.y = acc[i][5] + bv1.y;
        o1.z = acc[i][6] + bv1.z; o1.w = acc[i][7] + bv1.w;
        if (ACT == 1) {
            o0.x = tanhf(o0.x); o0.y = tanhf(o0.y); o0.z = tanhf(o0.z); o0.w = tanhf(o0.w);
            o1.x = tanhf(o1.x); o1.y = tanhf(o1.y); o1.z = tanhf(o1.z); o1.w = tanhf(o1.w);
        }
        *(float4*)(C + (size_t)row * Ncols + n0 + tx * 4) = o0;
        *(float4*)(C + (size_t)row * Ncols + n0 + 64 + tx * 4) = o1;
    }
}

__global__ __launch_bounds__(256) void bn_stats_kernel(const float* __restrict__ X,
                                                       float* __restrict__ sums)
{
    __shared__ float red[8][64];
    int lane = threadIdx.x & 63;
    int rl = threadIdx.x >> 6;
    int c = blockIdx.x * 64 + lane;
    int chunk = N_ROWS / gridDim.y;
    int rbeg = blockIdx.y * chunk;
    float s = 0.f, s2 = 0.f;
    for (int r = rbeg + rl; r < rbeg + chunk; r += 4) {
        float v = X[(size_t)r * DDIM + c];
        s += v; s2 += v * v;
    }
    red[rl][lane] = s; red[4 + rl][lane] = s2;
    __syncthreads();
    if (threadIdx.x < 64) {
        float ts = red[0][lane] + red[1][lane] + red[2][lane] + red[3][lane];
        float t2 = red[4][lane] + red[5][lane] + red[6][lane] + red[7][lane];
        atomicAdd(&sums[c], ts);
        atomicAdd(&sums[DDIM + c], t2);
    }
}

template<int TANH>
__global__ __launch_bounds__(256) void bn_apply_kernel(
    const float* __restrict__ X, float* __restrict__ Y,
    const float* __restrict__ sums, const float* __restrict__ g,
    const float* __restrict__ b, float invN)
{
    size_t i = (size_t)blockIdx.x * 256 + threadIdx.x;
    int cg = (int)(i % (DDIM / 4));
    int c = cg * 4;
    float4 x = ((const float4*)X)[i];
    float4 sm = *(const float4*)(sums + c);
    float4 sq = *(const float4*)(sums + DDIM + c);
    float4 gv = *(const float4*)(g + c);
    float4 bv = *(const float4*)(b + c);
    float m, var, rs;
    m = sm.x * invN; var = sq.x * invN - m * m; rs = rsqrtf(var + BN_EPS);
    x.x = (x.x - m) * rs * gv.x + bv.x;
    m = sm.y * invN; var = sq.y * invN - m * m; rs = rsqrtf(var + BN_EPS);
    x.y = (x.y - m) * rs * gv.y + bv.y;
    m = sm.z * invN; var = sq.z * invN - m * m; rs = rsqrtf(var + BN_EPS);
    x.z = (x.z - m) * rs * gv.z + bv.z;
    m = sm.w * invN; var = sq.w * invN - m * m; rs = rsqrtf(var + BN_EPS);
    x.w = (x.w - m) * rs * gv.w + bv.w;
    if (TANH) { x.x = tanhf(x.x); x.y = tanhf(x.y); x.z = tanhf(x.z); x.w = tanhf(x.w); }
    ((float4*)Y)[i] = x;
}

__global__ __launch_bounds__(256) void add_kernel(float* __restrict__ dst,
                                                  const float* __restrict__ src)
{
    size_t i = (size_t)blockIdx.x * 256 + threadIdx.x;
    float4 a = ((const float4*)dst)[i];
    float4 b = ((const float4*)src)[i];
    a.x += b.x; a.y += b.y; a.z += b.z; a.w += b.w;
    ((float4*)dst)[i] = a;
}

extern "C" void kernel_launch(void* const* d_in, const int* in_sizes, int n_in,
                              void* d_out, int out_size, void* d_ws, size_t ws_size,
                              hipStream_t stream)
{
    const float* src   = (const float*)d_in[0];
    const float* anc   = (const float*)d_in[1];
    const float* W_dim = (const float*)d_in[2];
    const float* b_dim = (const float*)d_in[3];
    const float* W_fus = (const float*)d_in[4];
    const float* b_fus = (const float*)d_in[5];
    const float* W_e1  = (const float*)d_in[6];
    const float* b_e1  = (const float*)d_in[7];
    const float* W_e2  = (const float*)d_in[8];
    const float* b_e2  = (const float*)d_in[9];
    const float* g1    = (const float*)d_in[10];
    const float* bt1   = (const float*)d_in[11];
    const float* g2    = (const float*)d_in[12];
    const float* bt2   = (const float*)d_in[13];
    const float* W_d   = (const float*)d_in[14];
    const float* b_d   = (const float*)d_in[15];
    const float* g_d   = (const float*)d_in[16];
    const float* bt_d  = (const float*)d_in[17];
    float* out = (float*)d_out;          // doubles as `comb`

    float* ws = (float*)d_ws;
    const size_t ND = (size_t)N_ROWS * DDIM;
    // layout (floats): [shared64 16.77M][bufA 8.39M][src2 12.58M][anc2 6.29M]
    //                  [norm_a 8192][sums 3072][bk 81920][bi 81920]  total 168.7 MB
    float* shared64 = ws;                         // score chunk OR network hidden
    float* bufA     = ws + 16777216;              // neigh -> enc2 out
    f16*   src2     = (f16*)(ws + 25165824);      // N x 1536
    f16*   anc2     = (f16*)(ws + 37748736);      // M x 1536
    float* norm_a   = ws + 44040192;
    float* sums1    = ws + 44048384;
    float* sums2    = sums1 + 1024;
    float* sums3    = sums2 + 1024;
    float* bk_state = ws + 44051456;
    int*   bi_state = (int*)(ws + 44133376);

    const float invN = 1.0f / (float)N_ROWS;
    float* score = shared64;
    float* bufC  = shared64;

    zero_kernel<<<dim3(12), 256, 0, stream>>>(sums1, 3072);
    init_state_kernel<<<dim3(320), 256, 0, stream>>>(bk_state, bi_state, N_ROWS * KNN);
    split_kernel<0><<<dim3(N_ROWS * DDIM / 1024), 256, 0, stream>>>(src, src2, N_ROWS);
    split_kernel<1><<<dim3(M_ANCH * DDIM / 1024), 256, 0, stream>>>(anc, anc2, M_ANCH);
    anchor_norm_kernel<<<dim3(M_ANCH / 4), 256, 0, stream>>>(anc, norm_a);

    // dist: 8 anchor chunks of 1024: MFMA GEMM -> score (64MB) -> top-5 scan
    for (int m0 = 0; m0 < M_ANCH; m0 += MCHUNK) {
        gemm_f16_nt<<<dim3(MCHUNK / 128, N_ROWS / 128), 256, 0, stream>>>(
            src2, anc2 + (size_t)m0 * KSPLIT, score, KSPLIT, MCHUNK);
        topk_scan_kernel<<<dim3(N_ROWS / 4), 256, 0, stream>>>(
            score, norm_a, bk_state, bi_state, m0);
    }
    gather_mean_kernel<<<dim3(N_ROWS / 4), 256, 0, stream>>>(anc, bi_state, bufA);

    // Phase 1 (chunked): a_map chunk + fused-concat -> comb (in d_out)
    for (int r0 = 0; r0 < N_ROWS; r0 += CHUNK) {
        gemm_kernel<0><<<dim3(DDIM / 128, CHUNK / 128), 256, 0, stream>>>(
            bufA + (size_t)r0 * DDIM, DDIM, nullptr, 0, W_dim, b_dim, bufC, DDIM);
        gemm_kernel<0><<<dim3(DDIM / 128, CHUNK / 128), 256, 0, stream>>>(
            src + (size_t)r0 * DDIM, DDIM, bufC, DDIM, W_fus, b_fus,
            out + (size_t)r0 * DDIM, DDIM);
    }
    bn_stats_kernel<<<dim3(DDIM / 64, 16), 256, 0, stream>>>(out, sums1);
    bn_apply_kernel<0><<<dim3(8192), 256, 0, stream>>>(out, out, sums1, g1, bt1, invN);

    // Phase 2 (chunked): h = tanh(comb@W_e1+b1) -> bufC ; t = h@W_e2+b2 -> bufA
    for (int r0 = 0; r0 < N_ROWS; r0 += CHUNK) {
        gemm_kernel<1><<<dim3(FDIM / 128, CHUNK / 128), 256, 0, stream>>>(
            out + (size_t)r0 * DDIM, DDIM, nullptr, 0, W_e1, b_e1, bufC, FDIM);
        gemm_kernel<0><<<dim3(DDIM / 128, CHUNK / 128), 256, 0, stream>>>(
            bufC, FDIM, nullptr, 0, W_e2, b_e2, bufA + (size_t)r0 * DDIM, DDIM);
    }
    add_kernel<<<dim3(8192), 256, 0, stream>>>(bufA, out);
    bn_stats_kernel<<<dim3(DDIM / 64, 16), 256, 0, stream>>>(bufA, sums2);
    bn_apply_kernel<0><<<dim3(8192), 256, 0, stream>>>(bufA, bufA, sums2, g2, bt2, invN);

    // decoder
    gemm_kernel<0><<<dim3(DDIM / 128, N_ROWS / 128), 256, 0, stream>>>(
        bufA, DDIM, nullptr, 0, W_d, b_d, out, DDIM);
    bn_stats_kernel<<<dim3(DDIM / 64, 16), 256, 0, stream>>>(out, sums3);
    bn_apply_kernel<1><<<dim3(8192), 256, 0, stream>>>(out, out, sums3, g_d, bt_d, invN);
}

// Round 4
// 3158.493 us; speedup vs baseline: 1.4748x; 1.2651x over previous
//
#include <hip/hip_runtime.h>
#include <math.h>

#define N_ROWS 16384
#define M_ANCH 8192
#define DDIM   512
#define FDIM   2048
#define KNN    5
#define BN_EPS 1e-5f
#define CHUNK  8192    // network-phase row chunk (h fp32 chunk = 64 MB, in score region)
#define MCHUNK 1024    // dist-phase anchor chunk (score buffer 64 MB)
#define KSPLIT 1536    // 3 x 512 virtual-K for dist hi/lo split product

typedef _Float16 f16;
typedef _Float16 f16x8 __attribute__((ext_vector_type(8)));
typedef _Float16 f16x4 __attribute__((ext_vector_type(4)));
typedef float f32x4 __attribute__((ext_vector_type(4)));

__device__ __forceinline__ void async_copy16(const void* g, void* l) {
    __builtin_amdgcn_global_load_lds(
        (const __attribute__((address_space(1))) void*)g,
        (__attribute__((address_space(3))) void*)l, 16, 0, 0);
}

__device__ __forceinline__ bool kless(float k1, int i1, float k2, int i2) {
    return (k1 < k2) || (k1 == k2 && i1 < i2);
}

__device__ __forceinline__ void insert5(float (&bk)[KNN], int (&bi)[KNN], float key, int id) {
    if (!kless(key, id, bk[4], bi[4])) return;
    bool c3 = kless(key, id, bk[3], bi[3]);
    bool c2 = kless(key, id, bk[2], bi[2]);
    bool c1 = kless(key, id, bk[1], bi[1]);
    bool c0 = kless(key, id, bk[0], bi[0]);
    bk[4] = c3 ? bk[3] : key;                  bi[4] = c3 ? bi[3] : id;
    bk[3] = c3 ? (c2 ? bk[2] : key) : bk[3];   bi[3] = c3 ? (c2 ? bi[2] : id) : bi[3];
    bk[2] = c2 ? (c1 ? bk[1] : key) : bk[2];   bi[2] = c2 ? (c1 ? bi[1] : id) : bi[2];
    bk[1] = c1 ? (c0 ? bk[0] : key) : bk[1];   bi[1] = c1 ? (c0 ? bi[0] : id) : bi[1];
    bk[0] = c0 ? key : bk[0];                  bi[0] = c0 ? id : bi[0];
}

__global__ void zero_kernel(float* p, int n) {
    int i = blockIdx.x * blockDim.x + threadIdx.x;
    if (i < n) p[i] = 0.f;
}

__global__ void init_state_kernel(float* bk, int* bi, int n) {
    int i = blockIdx.x * blockDim.x + threadIdx.x;
    if (i < n) { bk[i] = 3.0e38f; bi[i] = 0x7fffffff; }
}

// fp32 -> f16 hi/lo split into virtual-K layout (dist phase).
// MODE 0 (src): segs [hi | lo | hi];  MODE 1 (anchor): segs [hi | hi | lo]
template<int MODE>
__global__ __launch_bounds__(256) void split_kernel(const float* __restrict__ X,
                                                    f16* __restrict__ Y, int nrows) {
    int i4 = blockIdx.x * 256 + threadIdx.x;
    int row = i4 >> 7;
    int kc = (i4 & 127) * 4;
    if (row >= nrows) return;
    float4 v = ((const float4*)X)[i4];
    f16x4 h, lo;
    h.x = (f16)v.x; h.y = (f16)v.y; h.z = (f16)v.z; h.w = (f16)v.w;
    lo.x = (f16)(v.x - (float)h.x); lo.y = (f16)(v.y - (float)h.y);
    lo.z = (f16)(v.z - (float)h.z); lo.w = (f16)(v.w - (float)h.w);
    f16* base = Y + (size_t)row * KSPLIT + kc;
    if (MODE == 0) {
        *(f16x4*)(base) = h; *(f16x4*)(base + 512) = lo; *(f16x4*)(base + 1024) = h;
    } else {
        *(f16x4*)(base) = h; *(f16x4*)(base + 512) = h;  *(f16x4*)(base + 1024) = lo;
    }
}

__global__ __launch_bounds__(256) void anchor_norm_kernel(const float* __restrict__ a,
                                                          float* __restrict__ norm_a) {
    int wave = threadIdx.x >> 6, lane = threadIdx.x & 63;
    int row = blockIdx.x * 4 + wave;
    const float4* ar = (const float4*)(a + (size_t)row * DDIM);
    float4 v1 = ar[lane * 2];
    float4 v2 = ar[lane * 2 + 1];
    float s = v1.x*v1.x + v1.y*v1.y + v1.z*v1.z + v1.w*v1.w
            + v2.x*v2.x + v2.y*v2.y + v2.z*v2.z + v2.w*v2.w;
    for (int off = 32; off; off >>= 1) s += __shfl_xor(s, off, 64);
    if (lane == 0) norm_a[row] = s;
}

// dist-phase f16 NT GEMM (pre-split operands): C[m][n] = sum_k A[m][k]*B[n][k].
__global__ __launch_bounds__(256) void gemm_f16_nt(
    const f16* __restrict__ A, const f16* __restrict__ B,
    float* __restrict__ C, int K, int Ncols)
{
    __shared__ f16 As[128 * 32];
    __shared__ f16 Bs[128 * 32];
    const int t = threadIdx.x;
    const int w = t >> 6, l = t & 63;
    const int m0 = blockIdx.y * 128, n0 = blockIdx.x * 128;
    const int wm = (w & 1) * 64, wn = (w >> 1) * 64;

    f32x4 acc[4][4];
    #pragma unroll
    for (int i = 0; i < 4; ++i)
        #pragma unroll
        for (int j = 0; j < 4; ++j) acc[i][j] = (f32x4){0.f, 0.f, 0.f, 0.f};

    const int srow = l >> 2;
    const int skoff = (l & 3) * 8;

    for (int k0 = 0; k0 < K; k0 += 32) {
        __syncthreads();
        #pragma unroll
        for (int s = 0; s < 2; ++s) {
            int grp = w * 2 + s;
            int row = grp * 16 + srow;
            async_copy16(A + (size_t)(m0 + row) * K + k0 + skoff, As + grp * 512 + l * 8);
            async_copy16(B + (size_t)(n0 + row) * K + k0 + skoff, Bs + grp * 512 + l * 8);
        }
        __syncthreads();
        f16x8 af[4], bf[4];
        #pragma unroll
        for (int i = 0; i < 4; ++i)
            af[i] = *(const f16x8*)(As + (wm + i * 16 + (l & 15)) * 32 + (l >> 4) * 8);
        #pragma unroll
        for (int j = 0; j < 4; ++j)
            bf[j] = *(const f16x8*)(Bs + (wn + j * 16 + (l & 15)) * 32 + (l >> 4) * 8);
        #pragma unroll
        for (int i = 0; i < 4; ++i)
            #pragma unroll
            for (int j = 0; j < 4; ++j)
                acc[i][j] = __builtin_amdgcn_mfma_f32_16x16x32_f16(af[i], bf[j], acc[i][j], 0, 0, 0);
    }
    #pragma unroll
    for (int i = 0; i < 4; ++i)
        #pragma unroll
        for (int j = 0; j < 4; ++j)
            #pragma unroll
            for (int r = 0; r < 4; ++r) {
                int m = m0 + wm + i * 16 + (l >> 4) * 4 + r;
                int n = n0 + wn + j * 16 + (l & 15);
                C[(size_t)m * Ncols + n] = acc[i][j][r];
            }
}

// Network GEMM: C = act(A @ BwT + bias [+ C0]).  A fp32 [M,K] split in-kernel to
// f16 hi/lo LDS tiles; Bw pre-split f16 [N, hi(K)|lo(K)].  3-term product -> fp32-grade.
template<int ADDC0, int TANH>
__global__ __launch_bounds__(256) void gemm_split_nt(
    const float* __restrict__ A, const f16* __restrict__ Bw,
    const float* __restrict__ bias, const float* __restrict__ C0,
    float* __restrict__ C, int K, int Ncols)
{
    __shared__ f16 Ah[128 * 32];
    __shared__ f16 Al[128 * 32];
    __shared__ f16 Bh[128 * 32];
    __shared__ f16 Bl[128 * 32];
    const int t = threadIdx.x;
    const int w = t >> 6, l = t & 63;
    const int m0 = blockIdx.y * 128, n0 = blockIdx.x * 128;
    const int wm = (w & 1) * 64, wn = (w >> 1) * 64;
    const int K2 = 2 * K;

    f32x4 acc[4][4];
    #pragma unroll
    for (int i = 0; i < 4; ++i)
        #pragma unroll
        for (int j = 0; j < 4; ++j) acc[i][j] = (f32x4){0.f, 0.f, 0.f, 0.f};

    const int ar = t >> 1;           // A staging: row 0..127
    const int ac = (t & 1) * 16;     // k offset 0 or 16
    const int srow = l >> 2;         // B staging
    const int skoff = (l & 3) * 8;

    for (int k0 = 0; k0 < K; k0 += 32) {
        __syncthreads();
        // B: async global->LDS, hi and lo segments
        #pragma unroll
        for (int s = 0; s < 2; ++s) {
            int grp = w * 2 + s;
            int row = grp * 16 + srow;
            const f16* bp = Bw + (size_t)(n0 + row) * K2 + k0 + skoff;
            async_copy16(bp, Bh + grp * 512 + l * 8);
            async_copy16(bp + K, Bl + grp * 512 + l * 8);
        }
        // A: fp32 load + hi/lo split -> LDS
        {
            const float* ap = A + (size_t)(m0 + ar) * K + k0 + ac;
            float xs[16];
            *(float4*)&xs[0]  = *(const float4*)ap;
            *(float4*)&xs[4]  = *(const float4*)(ap + 4);
            *(float4*)&xs[8]  = *(const float4*)(ap + 8);
            *(float4*)&xs[12] = *(const float4*)(ap + 12);
            f16x8 h0, h1, lo0, lo1;
            #pragma unroll
            for (int e = 0; e < 8; ++e) {
                f16 hh = (f16)xs[e];
                h0[e] = hh; lo0[e] = (f16)(xs[e] - (float)hh);
                f16 hh2 = (f16)xs[8 + e];
                h1[e] = hh2; lo1[e] = (f16)(xs[8 + e] - (float)hh2);
            }
            *(f16x8*)&Ah[ar * 32 + ac] = h0;  *(f16x8*)&Ah[ar * 32 + ac + 8] = h1;
            *(f16x8*)&Al[ar * 32 + ac] = lo0; *(f16x8*)&Al[ar * 32 + ac + 8] = lo1;
        }
        __syncthreads();
        f16x8 afh[4], afl[4], bfh[4], bfl[4];
        #pragma unroll
        for (int i = 0; i < 4; ++i) {
            int base = (wm + i * 16 + (l & 15)) * 32 + (l >> 4) * 8;
            afh[i] = *(const f16x8*)(Ah + base);
            afl[i] = *(const f16x8*)(Al + base);
        }
        #pragma unroll
        for (int j = 0; j < 4; ++j) {
            int base = (wn + j * 16 + (l & 15)) * 32 + (l >> 4) * 8;
            bfh[j] = *(const f16x8*)(Bh + base);
            bfl[j] = *(const f16x8*)(Bl + base);
        }
        #pragma unroll
        for (int i = 0; i < 4; ++i)
            #pragma unroll
            for (int j = 0; j < 4; ++j) {
                acc[i][j] = __builtin_amdgcn_mfma_f32_16x16x32_f16(afh[i], bfh[j], acc[i][j], 0, 0, 0);
                acc[i][j] = __builtin_amdgcn_mfma_f32_16x16x32_f16(afl[i], bfh[j], acc[i][j], 0, 0, 0);
                acc[i][j] = __builtin_amdgcn_mfma_f32_16x16x32_f16(afh[i], bfl[j], acc[i][j], 0, 0, 0);
            }
    }
    float bv[4];
    #pragma unroll
    for (int j = 0; j < 4; ++j)
        bv[j] = bias ? bias[n0 + wn + j * 16 + (l & 15)] : 0.f;
    #pragma unroll
    for (int i = 0; i < 4; ++i)
        #pragma unroll
        for (int j = 0; j < 4; ++j)
            #pragma unroll
            for (int r = 0; r < 4; ++r) {
                int m = m0 + wm + i * 16 + (l >> 4) * 4 + r;
                int n = n0 + wn + j * 16 + (l & 15);
                float v = acc[i][j][r] + bv[j];
                if (ADDC0) v += C0[(size_t)m * Ncols + n];
                if (TANH)  v = tanhf(v);
                C[(size_t)m * Ncols + n] = v;
            }
}

// Weight transpose + hi/lo split: W [K,N] fp32 -> Wt [N, hi(K)|lo(K)] f16.
__global__ __launch_bounds__(256) void wsplit_kernel(const float* __restrict__ W,
                                                     f16* __restrict__ Wt,
                                                     int K, int N)
{
    __shared__ float tile[64][65];
    const int t = threadIdx.x;
    const int kb = blockIdx.y * 64, nb = blockIdx.x * 64;
    #pragma unroll
    for (int i = 0; i < 4; ++i) {
        int r = (t >> 4) + i * 16;
        int c = (t & 15) * 4;
        *(float4*)&tile[r][c] = *(const float4*)&W[(size_t)(kb + r) * N + nb + c];
    }
    __syncthreads();
    const int r2 = t >> 2;           // output row (n) within tile
    const int kc = (t & 3) * 16;     // k offset within tile
    f16x8 h0, h1, lo0, lo1;
    #pragma unroll
    for (int e = 0; e < 8; ++e) {
        float x = tile[kc + e][r2];
        f16 hh = (f16)x; h0[e] = hh; lo0[e] = (f16)(x - (float)hh);
        float y = tile[kc + 8 + e][r2];
        f16 hh2 = (f16)y; h1[e] = hh2; lo1[e] = (f16)(y - (float)hh2);
    }
    f16* base = Wt + (size_t)(nb + r2) * 2 * K + kb + kc;
    *(f16x8*)base = h0; *(f16x8*)(base + 8) = h1;
    *(f16x8*)(base + K) = lo0; *(f16x8*)(base + K + 8) = lo1;
}

// b_comb[n] = sum_k b_dim[k] * W_fus[512+k][n] + b_fus[n]
__global__ __launch_bounds__(256) void bcomb_kernel(const float* __restrict__ b_dim,
                                                    const float* __restrict__ W_fus2,
                                                    const float* __restrict__ b_fus,
                                                    float* __restrict__ b_comb)
{
    int n = blockIdx.x * 256 + threadIdx.x;
    if (n >= DDIM) return;
    float s = b_fus[n];
    for (int k = 0; k < DDIM; ++k) s += b_dim[k] * W_fus2[(size_t)k * DDIM + n];
    b_comb[n] = s;
}

// top-5 scan over one score chunk; persistent state in ws. One wave per src row.
__global__ __launch_bounds__(256) void topk_scan_kernel(
    const float* __restrict__ g, const float* __restrict__ norm_a,
    float* __restrict__ bk_state, int* __restrict__ bi_state, int m0)
{
    int row = blockIdx.x * 4 + (threadIdx.x >> 6);
    int lane = threadIdx.x & 63;
    float bk[KNN]; int bi[KNN];
    #pragma unroll
    for (int q = 0; q < KNN; ++q) { bk[q] = 3.0e38f; bi[q] = 0x7fffffff; }

    const float* grow = g + (size_t)row * MCHUNK;
    #pragma unroll
    for (int it = 0; it < MCHUNK / 256; ++it) {
        int col = it * 256 + lane * 4;
        float4 gv = *(const float4*)(grow + col);
        float4 nv = *(const float4*)(norm_a + m0 + col);
        insert5(bk, bi, nv.x - 2.f * gv.x, m0 + col);
        insert5(bk, bi, nv.y - 2.f * gv.y, m0 + col + 1);
        insert5(bk, bi, nv.z - 2.f * gv.z, m0 + col + 2);
        insert5(bk, bi, nv.w - 2.f * gv.w, m0 + col + 3);
    }
    for (int off = 32; off >= 1; off >>= 1) {
        float ok[KNN]; int oi[KNN];
        #pragma unroll
        for (int q = 0; q < KNN; ++q) {
            ok[q] = __shfl_xor(bk[q], off, 64);
            oi[q] = __shfl_xor(bi[q], off, 64);
        }
        #pragma unroll
        for (int q = 0; q < KNN; ++q) insert5(bk, bi, ok[q], oi[q]);
    }
    if (lane == 0) {
        #pragma unroll
        for (int q = 0; q < KNN; ++q)
            insert5(bk, bi, bk_state[row * KNN + q], bi_state[row * KNN + q]);
        #pragma unroll
        for (int q = 0; q < KNN; ++q) {
            bk_state[row * KNN + q] = bk[q];
            bi_state[row * KNN + q] = bi[q];
        }
    }
}

__global__ __launch_bounds__(256) void gather_mean_kernel(
    const float* __restrict__ anchor, const int* __restrict__ bi_state,
    float* __restrict__ neigh)
{
    int row = blockIdx.x * 4 + (threadIdx.x >> 6);
    int lane = threadIdx.x & 63;
    const int* bi = bi_state + row * KNN;
    int i0 = bi[0], i1 = bi[1], i2 = bi[2], i3 = bi[3], i4 = bi[4];
    const float4* a0 = (const float4*)(anchor + (size_t)i0 * DDIM);
    const float4* a1 = (const float4*)(anchor + (size_t)i1 * DDIM);
    const float4* a2 = (const float4*)(anchor + (size_t)i2 * DDIM);
    const float4* a3 = (const float4*)(anchor + (size_t)i3 * DDIM);
    const float4* a4 = (const float4*)(anchor + (size_t)i4 * DDIM);
    float4* np = (float4*)(neigh + (size_t)row * DDIM);
    #pragma unroll
    for (int p = 0; p < 2; ++p) {
        int c4 = lane + 64 * p;
        float4 v0 = a0[c4], v1 = a1[c4], v2 = a2[c4], v3 = a3[c4], v4 = a4[c4];
        float4 o;
        o.x = (v0.x + v1.x + v2.x + v3.x + v4.x) * 0.2f;
        o.y = (v0.y + v1.y + v2.y + v3.y + v4.y) * 0.2f;
        o.z = (v0.z + v1.z + v2.z + v3.z + v4.z) * 0.2f;
        o.w = (v0.w + v1.w + v2.w + v3.w + v4.w) * 0.2f;
        np[c4] = o;
    }
}

// fp32 GEMM (used only for the tiny W_comb2 = W_dim @ W_fus2 fold).
template<int ACT>
__global__ __launch_bounds__(256) void gemm_kernel(
    const float* __restrict__ A, int K1,
    const float* __restrict__ A2, int K2,
    const float* __restrict__ B, const float* __restrict__ bias,
    float* __restrict__ C, int Ncols)
{
    __shared__ float As[16][132];
    __shared__ float Bs[16][128];
    const int t = threadIdx.x;
    const int n0 = blockIdx.x * 128;
    const int m0 = blockIdx.y * 128;
    const int ty = t >> 4, tx = t & 15;
    const int K = K1 + K2;

    float acc[8][8];
    #pragma unroll
    for (int i = 0; i < 8; ++i)
        #pragma unroll
        for (int j = 0; j < 8; ++j) acc[i][j] = 0.f;

    const int ar = t >> 1;
    const int akc = (t & 1) * 8;
    const int bkr = t >> 4;
    const int bc = (t & 15) * 8;

    for (int k0 = 0; k0 < K; k0 += 16) {
        int kk = k0 + akc;
        float4 v0, v1;
        if (kk < K1) {
            const float* p = A + (size_t)(m0 + ar) * K1 + kk;
            v0 = *(const float4*)p; v1 = *(const float4*)(p + 4);
        } else {
            const float* p = A2 + (size_t)(m0 + ar) * K2 + (kk - K1);
            v0 = *(const float4*)p; v1 = *(const float4*)(p + 4);
        }
        const float* bp = B + (size_t)(k0 + bkr) * Ncols + n0 + bc;
        float4 w0 = *(const float4*)bp, w1 = *(const float4*)(bp + 4);
        __syncthreads();
        As[akc+0][ar] = v0.x; As[akc+1][ar] = v0.y; As[akc+2][ar] = v0.z; As[akc+3][ar] = v0.w;
        As[akc+4][ar] = v1.x; As[akc+5][ar] = v1.y; As[akc+6][ar] = v1.z; As[akc+7][ar] = v1.w;
        *(float4*)&Bs[bkr][bc] = w0; *(float4*)&Bs[bkr][bc + 4] = w1;
        __syncthreads();
        #pragma unroll
        for (int k = 0; k < 16; ++k) {
            float a[8], b[8];
            *(float4*)&a[0] = *(const float4*)&As[k][ty * 8];
            *(float4*)&a[4] = *(const float4*)&As[k][ty * 8 + 4];
            *(float4*)&b[0] = *(const float4*)&Bs[k][tx * 4];
            *(float4*)&b[4] = *(const float4*)&Bs[k][64 + tx * 4];
            #pragma unroll
            for (int i = 0; i < 8; ++i)
                #pragma unroll
                for (int j = 0; j < 8; ++j) acc[i][j] += a[i] * b[j];
        }
    }
    float4 bv0 = *(const float4*)(bias + n0 + tx * 4);
    float4 bv1 = *(const float4*)(bias + n0 + 64 + tx * 4);
    #pragma unroll
    for (int i = 0; i < 8; ++i) {
        int row = m0 + ty * 8 + i;
        float4 o0, o1;
        o0.x = acc[i][0] + bv0.x; o0.y = acc[i][1] + bv0.y;
        o0.z = acc[i][2] + bv0.z; o0.w = acc[i][3] + bv0.w;
        o1.x = acc[i][4] + bv1.x; o1.y = acc[i][5] + bv1.y;
        o1.z = acc[i][6] + bv1.z; o1.w = acc[i][7] + bv1.w;
        if (ACT == 1) {
            o0.x = tanhf(o0.x); o0.y = tanhf(o0.y); o0.z = tanhf(o0.z); o0.w = tanhf(o0.w);
            o1.x = tanhf(o1.x); o1.y = tanhf(o1.y); o1.z = tanhf(o1.z); o1.w = tanhf(o1.w);
        }
        *(float4*)(C + (size_t)row * Ncols + n0 + tx * 4) = o0;
        *(float4*)(C + (size_t)row * Ncols + n0 + 64 + tx * 4) = o1;
    }
}

__global__ __launch_bounds__(256) void bn_stats_kernel(const float* __restrict__ X,
                                                       float* __restrict__ sums)
{
    __shared__ float red[8][64];
    int lane = threadIdx.x & 63;
    int rl = threadIdx.x >> 6;
    int c = blockIdx.x * 64 + lane;
    int chunk = N_ROWS / gridDim.y;
    int rbeg = blockIdx.y * chunk;
    float s = 0.f, s2 = 0.f;
    for (int r = rbeg + rl; r < rbeg + chunk; r += 4) {
        float v = X[(size_t)r * DDIM + c];
        s += v; s2 += v * v;
    }
    red[rl][lane] = s; red[4 + rl][lane] = s2;
    __syncthreads();
    if (threadIdx.x < 64) {
        float ts = red[0][lane] + red[1][lane] + red[2][lane] + red[3][lane];
        float t2 = red[4][lane] + red[5][lane] + red[6][lane] + red[7][lane];
        atomicAdd(&sums[c], ts);
        atomicAdd(&sums[DDIM + c], t2);
    }
}

template<int TANH>
__global__ __launch_bounds__(256) void bn_apply_kernel(
    const float* __restrict__ X, float* __restrict__ Y,
    const float* __restrict__ sums, const float* __restrict__ g,
    const float* __restrict__ b, float invN)
{
    size_t i = (size_t)blockIdx.x * 256 + threadIdx.x;
    int cg = (int)(i % (DDIM / 4));
    int c = cg * 4;
    float4 x = ((const float4*)X)[i];
    float4 sm = *(const float4*)(sums + c);
    float4 sq = *(const float4*)(sums + DDIM + c);
    float4 gv = *(const float4*)(g + c);
    float4 bv = *(const float4*)(b + c);
    float m, var, rs;
    m = sm.x * invN; var = sq.x * invN - m * m; rs = rsqrtf(var + BN_EPS);
    x.x = (x.x - m) * rs * gv.x + bv.x;
    m = sm.y * invN; var = sq.y * invN - m * m; rs = rsqrtf(var + BN_EPS);
    x.y = (x.y - m) * rs * gv.y + bv.y;
    m = sm.z * invN; var = sq.z * invN - m * m; rs = rsqrtf(var + BN_EPS);
    x.z = (x.z - m) * rs * gv.z + bv.z;
    m = sm.w * invN; var = sq.w * invN - m * m; rs = rsqrtf(var + BN_EPS);
    x.w = (x.w - m) * rs * gv.w + bv.w;
    if (TANH) { x.x = tanhf(x.x); x.y = tanhf(x.y); x.z = tanhf(x.z); x.w = tanhf(x.w); }
    ((float4*)Y)[i] = x;
}

extern "C" void kernel_launch(void* const* d_in, const int* in_sizes, int n_in,
                              void* d_out, int out_size, void* d_ws, size_t ws_size,
                              hipStream_t stream)
{
    const float* src   = (const float*)d_in[0];
    const float* anc   = (const float*)d_in[1];
    const float* W_dim = (const float*)d_in[2];
    const float* b_dim = (const float*)d_in[3];
    const float* W_fus = (const float*)d_in[4];
    const float* b_fus = (const float*)d_in[5];
    const float* W_e1  = (const float*)d_in[6];
    const float* b_e1  = (const float*)d_in[7];
    const float* W_e2  = (const float*)d_in[8];
    const float* b_e2  = (const float*)d_in[9];
    const float* g1    = (const float*)d_in[10];
    const float* bt1   = (const float*)d_in[11];
    const float* g2    = (const float*)d_in[12];
    const float* bt2   = (const float*)d_in[13];
    const float* W_d   = (const float*)d_in[14];
    const float* b_d   = (const float*)d_in[15];
    const float* g_d   = (const float*)d_in[16];
    const float* bt_d  = (const float*)d_in[17];
    float* out = (float*)d_out;          // doubles as `comb`

    float* ws = (float*)d_ws;
    // Layout (floats), total 44,478,464 fl = 177.9 MB:
    //  [0)            score (dist) / h fp32 chunk (network)   16,777,216
    //  [16,777,216)   bufA: neigh -> enc2-out(t)               8,388,608
    //  [25,165,824)   dist: src2+anc2 f16  |  network: weight f16 overlay
    //  [44,040,192)   W_comb2 fp32 262,144
    //  [44,302,336)   norm_a 8192 | sums 3072 | zeros 512 | b_comb 512 | bk/bi
    float* score  = ws;
    float* bufA   = ws + 16777216;
    f16*   src2   = (f16*)(ws + 25165824);     // 16384 x 1536 f16
    f16*   anc2   = (f16*)(ws + 37748736);     // 8192 x 1536 f16
    f16*   wbase  = (f16*)(ws + 25165824);     // weight overlay (after dist)
    f16*   Wt_fus1  = wbase;                   // [512, 1024]
    f16*   Wt_comb2 = wbase + 524288;          // [512, 1024]
    f16*   Wt_e1    = wbase + 1048576;         // [2048, 1024]
    f16*   Wt_e2    = wbase + 3145728;         // [512, 4096]
    f16*   Wt_d     = wbase + 5242880;         // [512, 1024]
    float* W_comb2  = ws + 44040192;
    float* norm_a   = ws + 44302336;
    float* sums1    = ws + 44310528;
    float* sums2    = sums1 + 1024;
    float* sums3    = sums2 + 1024;
    float* zeros512 = ws + 44313600;
    float* b_comb   = ws + 44314112;
    float* bk_state = ws + 44314624;
    int*   bi_state = (int*)(ws + 44396544);

    const float invN = 1.0f / (float)N_ROWS;
    float* hbuf = score;   // network-phase alias

    zero_kernel<<<dim3(14), 256, 0, stream>>>(sums1, 3584);   // sums1..3 + zeros512
    init_state_kernel<<<dim3(320), 256, 0, stream>>>(bk_state, bi_state, N_ROWS * KNN);
    split_kernel<0><<<dim3(N_ROWS * DDIM / 1024), 256, 0, stream>>>(src, src2, N_ROWS);
    split_kernel<1><<<dim3(M_ANCH * DDIM / 1024), 256, 0, stream>>>(anc, anc2, M_ANCH);
    anchor_norm_kernel<<<dim3(M_ANCH / 4), 256, 0, stream>>>(anc, norm_a);

    // dist: 8 anchor chunks: MFMA GEMM -> score -> top-5 scan
    for (int m0 = 0; m0 < M_ANCH; m0 += MCHUNK) {
        gemm_f16_nt<<<dim3(MCHUNK / 128, N_ROWS / 128), 256, 0, stream>>>(
            src2, anc2 + (size_t)m0 * KSPLIT, score, KSPLIT, MCHUNK);
        topk_scan_kernel<<<dim3(N_ROWS / 4), 256, 0, stream>>>(
            score, norm_a, bk_state, bi_state, m0);
    }
    gather_mean_kernel<<<dim3(N_ROWS / 4), 256, 0, stream>>>(anc, bi_state, bufA);

    // Weight prep (overlays dead src2/anc2 region)
    wsplit_kernel<<<dim3(DDIM / 64, DDIM / 64), 256, 0, stream>>>(W_fus, Wt_fus1, DDIM, DDIM);
    wsplit_kernel<<<dim3(FDIM / 64, DDIM / 64), 256, 0, stream>>>(W_e1, Wt_e1, DDIM, FDIM);
    wsplit_kernel<<<dim3(DDIM / 64, FDIM / 64), 256, 0, stream>>>(W_e2, Wt_e2, FDIM, DDIM);
    wsplit_kernel<<<dim3(DDIM / 64, DDIM / 64), 256, 0, stream>>>(W_d, Wt_d, DDIM, DDIM);
    // W_comb2 = W_dim @ W_fus[512:,:]; b_comb = b_dim @ W_fus[512:,:] + b_fus
    gemm_kernel<0><<<dim3(4, 4), 256, 0, stream>>>(
        W_dim, DDIM, nullptr, 0, W_fus + DDIM * DDIM, zeros512, W_comb2, DDIM);
    bcomb_kernel<<<dim3(2), 256, 0, stream>>>(b_dim, W_fus + DDIM * DDIM, b_fus, b_comb);
    wsplit_kernel<<<dim3(DDIM / 64, DDIM / 64), 256, 0, stream>>>(W_comb2, Wt_comb2, DDIM, DDIM);

    // comb = src @ Wf1 + b_comb + neigh @ W_comb2   -> out, then BN1
    gemm_split_nt<0, 0><<<dim3(DDIM / 128, N_ROWS / 128), 256, 0, stream>>>(
        src, Wt_fus1, b_comb, nullptr, out, DDIM, DDIM);
    gemm_split_nt<1, 0><<<dim3(DDIM / 128, N_ROWS / 128), 256, 0, stream>>>(
        bufA, Wt_comb2, nullptr, out, out, DDIM, DDIM);
    bn_stats_kernel<<<dim3(DDIM / 64, 16), 256, 0, stream>>>(out, sums1);
    bn_apply_kernel<0><<<dim3(8192), 256, 0, stream>>>(out, out, sums1, g1, bt1, invN);

    // encoder, chunked: h = tanh(comb@We1+b1); t = h@We2 + b2 + comb
    for (int r0 = 0; r0 < N_ROWS; r0 += CHUNK) {
        gemm_split_nt<0, 1><<<dim3(FDIM / 128, CHUNK / 128), 256, 0, stream>>>(
            out + (size_t)r0 * DDIM, Wt_e1, b_e1, nullptr, hbuf, DDIM, FDIM);
        gemm_split_nt<1, 0><<<dim3(DDIM / 128, CHUNK / 128), 256, 0, stream>>>(
            hbuf, Wt_e2, b_e2, out + (size_t)r0 * DDIM, bufA + (size_t)r0 * DDIM,
            FDIM, DDIM);
    }
    bn_stats_kernel<<<dim3(DDIM / 64, 16), 256, 0, stream>>>(bufA, sums2);
    bn_apply_kernel<0><<<dim3(8192), 256, 0, stream>>>(bufA, bufA, sums2, g2, bt2, invN);

    // decoder -> out, BN3 + tanh
    gemm_split_nt<0, 0><<<dim3(DDIM / 128, N_ROWS / 128), 256, 0, stream>>>(
        bufA, Wt_d, b_d, nullptr, out, DDIM, DDIM);
    bn_stats_kernel<<<dim3(DDIM / 64, 16), 256, 0, stream>>>(out, sums3);
    bn_apply_kernel<1><<<dim3(8192), 256, 0, stream>>>(out, out, sums3, g_d, bt_d, invN);
}

// Round 5
// 2797.690 us; speedup vs baseline: 1.6651x; 1.1290x over previous
//
#include <hip/hip_runtime.h>
#include <math.h>

#define N_ROWS 16384
#define M_ANCH 8192
#define DDIM   512
#define FDIM   2048
#define KNN    5
#define BN_EPS 1e-5f
#define CHUNK  8192    // network-phase row chunk (h fp32 chunk = 64 MB, in score region)
#define MCHUNK 1024    // dist-phase anchor chunk (score buffer 64 MB)
#define KSPLIT 1536    // 3 x 512 virtual-K for dist hi/lo split product

typedef _Float16 f16;
typedef _Float16 f16x8 __attribute__((ext_vector_type(8)));
typedef _Float16 f16x4 __attribute__((ext_vector_type(4)));
typedef float f32x4 __attribute__((ext_vector_type(4)));

__device__ __forceinline__ void async_copy16(const void* g, void* l) {
    __builtin_amdgcn_global_load_lds(
        (const __attribute__((address_space(1))) void*)g,
        (__attribute__((address_space(3))) void*)l, 16, 0, 0);
}

__device__ __forceinline__ bool kless(float k1, int i1, float k2, int i2) {
    return (k1 < k2) || (k1 == k2 && i1 < i2);
}

__device__ __forceinline__ void insert5(float (&bk)[KNN], int (&bi)[KNN], float key, int id) {
    if (!kless(key, id, bk[4], bi[4])) return;
    bool c3 = kless(key, id, bk[3], bi[3]);
    bool c2 = kless(key, id, bk[2], bi[2]);
    bool c1 = kless(key, id, bk[1], bi[1]);
    bool c0 = kless(key, id, bk[0], bi[0]);
    bk[4] = c3 ? bk[3] : key;                  bi[4] = c3 ? bi[3] : id;
    bk[3] = c3 ? (c2 ? bk[2] : key) : bk[3];   bi[3] = c3 ? (c2 ? bi[2] : id) : bi[3];
    bk[2] = c2 ? (c1 ? bk[1] : key) : bk[2];   bi[2] = c2 ? (c1 ? bi[1] : id) : bi[2];
    bk[1] = c1 ? (c0 ? bk[0] : key) : bk[1];   bi[1] = c1 ? (c0 ? bi[0] : id) : bi[1];
    bk[0] = c0 ? key : bk[0];                  bi[0] = c0 ? id : bi[0];
}

__global__ void zero_kernel(float* p, int n) {
    int i = blockIdx.x * blockDim.x + threadIdx.x;
    if (i < n) p[i] = 0.f;
}

__global__ void init_state_kernel(float* bk, int* bi, int n) {
    int i = blockIdx.x * blockDim.x + threadIdx.x;
    if (i < n) { bk[i] = 3.0e38f; bi[i] = 0x7fffffff; }
}

// fp32 -> f16 hi/lo split into virtual-K layout (dist phase).
// MODE 0 (src): segs [hi | lo | hi];  MODE 1 (anchor): segs [hi | hi | lo]
template<int MODE>
__global__ __launch_bounds__(256) void split_kernel(const float* __restrict__ X,
                                                    f16* __restrict__ Y, int nrows) {
    int i4 = blockIdx.x * 256 + threadIdx.x;
    int row = i4 >> 7;
    int kc = (i4 & 127) * 4;
    if (row >= nrows) return;
    float4 v = ((const float4*)X)[i4];
    f16x4 h, lo;
    h.x = (f16)v.x; h.y = (f16)v.y; h.z = (f16)v.z; h.w = (f16)v.w;
    lo.x = (f16)(v.x - (float)h.x); lo.y = (f16)(v.y - (float)h.y);
    lo.z = (f16)(v.z - (float)h.z); lo.w = (f16)(v.w - (float)h.w);
    f16* base = Y + (size_t)row * KSPLIT + kc;
    if (MODE == 0) {
        *(f16x4*)(base) = h; *(f16x4*)(base + 512) = lo; *(f16x4*)(base + 1024) = h;
    } else {
        *(f16x4*)(base) = h; *(f16x4*)(base + 512) = h;  *(f16x4*)(base + 1024) = lo;
    }
}

__global__ __launch_bounds__(256) void anchor_norm_kernel(const float* __restrict__ a,
                                                          float* __restrict__ norm_a) {
    int wave = threadIdx.x >> 6, lane = threadIdx.x & 63;
    int row = blockIdx.x * 4 + wave;
    const float4* ar = (const float4*)(a + (size_t)row * DDIM);
    float4 v1 = ar[lane * 2];
    float4 v2 = ar[lane * 2 + 1];
    float s = v1.x*v1.x + v1.y*v1.y + v1.z*v1.z + v1.w*v1.w
            + v2.x*v2.x + v2.y*v2.y + v2.z*v2.z + v2.w*v2.w;
    for (int off = 32; off; off >>= 1) s += __shfl_xor(s, off, 64);
    if (lane == 0) norm_a[row] = s;
}

// dist-phase f16 NT GEMM (pre-split operands): C[m][n] = sum_k A[m][k]*B[n][k].
__global__ __launch_bounds__(256) void gemm_f16_nt(
    const f16* __restrict__ A, const f16* __restrict__ B,
    float* __restrict__ C, int K, int Ncols)
{
    __shared__ f16 As[128 * 32];
    __shared__ f16 Bs[128 * 32];
    const int t = threadIdx.x;
    const int w = t >> 6, l = t & 63;
    const int m0 = blockIdx.y * 128, n0 = blockIdx.x * 128;
    const int wm = (w & 1) * 64, wn = (w >> 1) * 64;

    f32x4 acc[4][4];
    #pragma unroll
    for (int i = 0; i < 4; ++i)
        #pragma unroll
        for (int j = 0; j < 4; ++j) acc[i][j] = (f32x4){0.f, 0.f, 0.f, 0.f};

    const int srow = l >> 2;
    const int skoff = (l & 3) * 8;

    for (int k0 = 0; k0 < K; k0 += 32) {
        __syncthreads();
        #pragma unroll
        for (int s = 0; s < 2; ++s) {
            int grp = w * 2 + s;
            int row = grp * 16 + srow;
            async_copy16(A + (size_t)(m0 + row) * K + k0 + skoff, As + grp * 512 + l * 8);
            async_copy16(B + (size_t)(n0 + row) * K + k0 + skoff, Bs + grp * 512 + l * 8);
        }
        __syncthreads();
        f16x8 af[4], bf[4];
        #pragma unroll
        for (int i = 0; i < 4; ++i)
            af[i] = *(const f16x8*)(As + (wm + i * 16 + (l & 15)) * 32 + (l >> 4) * 8);
        #pragma unroll
        for (int j = 0; j < 4; ++j)
            bf[j] = *(const f16x8*)(Bs + (wn + j * 16 + (l & 15)) * 32 + (l >> 4) * 8);
        #pragma unroll
        for (int i = 0; i < 4; ++i)
            #pragma unroll
            for (int j = 0; j < 4; ++j)
                acc[i][j] = __builtin_amdgcn_mfma_f32_16x16x32_f16(af[i], bf[j], acc[i][j], 0, 0, 0);
    }
    #pragma unroll
    for (int i = 0; i < 4; ++i)
        #pragma unroll
        for (int j = 0; j < 4; ++j)
            #pragma unroll
            for (int r = 0; r < 4; ++r) {
                int m = m0 + wm + i * 16 + (l >> 4) * 4 + r;
                int n = n0 + wn + j * 16 + (l & 15);
                C[(size_t)m * Ncols + n] = acc[i][j][r];
            }
}

// Network GEMM: C = act(A @ BwT + bias [+ C0]).  A fp32 [M,K] split in-kernel to
// f16 hi/lo LDS tiles; Bw pre-split f16 [N, hi(K)|lo(K)].  3-term product -> fp32-grade.
template<int ADDC0, int TANH>
__global__ __launch_bounds__(256) void gemm_split_nt(
    const float* __restrict__ A, const f16* __restrict__ Bw,
    const float* __restrict__ bias, const float* __restrict__ C0,
    float* __restrict__ C, int K, int Ncols)
{
    __shared__ f16 Ah[128 * 32];
    __shared__ f16 Al[128 * 32];
    __shared__ f16 Bh[128 * 32];
    __shared__ f16 Bl[128 * 32];
    const int t = threadIdx.x;
    const int w = t >> 6, l = t & 63;
    const int m0 = blockIdx.y * 128, n0 = blockIdx.x * 128;
    const int wm = (w & 1) * 64, wn = (w >> 1) * 64;
    const int K2 = 2 * K;

    f32x4 acc[4][4];
    #pragma unroll
    for (int i = 0; i < 4; ++i)
        #pragma unroll
        for (int j = 0; j < 4; ++j) acc[i][j] = (f32x4){0.f, 0.f, 0.f, 0.f};

    const int ar = t >> 1;           // A staging: row 0..127
    const int ac = (t & 1) * 16;     // k offset 0 or 16
    const int srow = l >> 2;         // B staging
    const int skoff = (l & 3) * 8;

    for (int k0 = 0; k0 < K; k0 += 32) {
        __syncthreads();
        // B: async global->LDS, hi and lo segments
        #pragma unroll
        for (int s = 0; s < 2; ++s) {
            int grp = w * 2 + s;
            int row = grp * 16 + srow;
            const f16* bp = Bw + (size_t)(n0 + row) * K2 + k0 + skoff;
            async_copy16(bp, Bh + grp * 512 + l * 8);
            async_copy16(bp + K, Bl + grp * 512 + l * 8);
        }
        // A: fp32 load + hi/lo split -> LDS
        {
            const float* ap = A + (size_t)(m0 + ar) * K + k0 + ac;
            float xs[16];
            *(float4*)&xs[0]  = *(const float4*)ap;
            *(float4*)&xs[4]  = *(const float4*)(ap + 4);
            *(float4*)&xs[8]  = *(const float4*)(ap + 8);
            *(float4*)&xs[12] = *(const float4*)(ap + 12);
            f16x8 h0, h1, lo0, lo1;
            #pragma unroll
            for (int e = 0; e < 8; ++e) {
                f16 hh = (f16)xs[e];
                h0[e] = hh; lo0[e] = (f16)(xs[e] - (float)hh);
                f16 hh2 = (f16)xs[8 + e];
                h1[e] = hh2; lo1[e] = (f16)(xs[8 + e] - (float)hh2);
            }
            *(f16x8*)&Ah[ar * 32 + ac] = h0;  *(f16x8*)&Ah[ar * 32 + ac + 8] = h1;
            *(f16x8*)&Al[ar * 32 + ac] = lo0; *(f16x8*)&Al[ar * 32 + ac + 8] = lo1;
        }
        __syncthreads();
        f16x8 afh[4], afl[4], bfh[4], bfl[4];
        #pragma unroll
        for (int i = 0; i < 4; ++i) {
            int base = (wm + i * 16 + (l & 15)) * 32 + (l >> 4) * 8;
            afh[i] = *(const f16x8*)(Ah + base);
            afl[i] = *(const f16x8*)(Al + base);
        }
        #pragma unroll
        for (int j = 0; j < 4; ++j) {
            int base = (wn + j * 16 + (l & 15)) * 32 + (l >> 4) * 8;
            bfh[j] = *(const f16x8*)(Bh + base);
            bfl[j] = *(const f16x8*)(Bl + base);
        }
        #pragma unroll
        for (int i = 0; i < 4; ++i)
            #pragma unroll
            for (int j = 0; j < 4; ++j) {
                acc[i][j] = __builtin_amdgcn_mfma_f32_16x16x32_f16(afh[i], bfh[j], acc[i][j], 0, 0, 0);
                acc[i][j] = __builtin_amdgcn_mfma_f32_16x16x32_f16(afl[i], bfh[j], acc[i][j], 0, 0, 0);
                acc[i][j] = __builtin_amdgcn_mfma_f32_16x16x32_f16(afh[i], bfl[j], acc[i][j], 0, 0, 0);
            }
    }
    float bv[4];
    #pragma unroll
    for (int j = 0; j < 4; ++j)
        bv[j] = bias ? bias[n0 + wn + j * 16 + (l & 15)] : 0.f;
    #pragma unroll
    for (int i = 0; i < 4; ++i)
        #pragma unroll
        for (int j = 0; j < 4; ++j)
            #pragma unroll
            for (int r = 0; r < 4; ++r) {
                int m = m0 + wm + i * 16 + (l >> 4) * 4 + r;
                int n = n0 + wn + j * 16 + (l & 15);
                float v = acc[i][j][r] + bv[j];
                if (ADDC0) v += C0[(size_t)m * Ncols + n];
                if (TANH)  v = tanhf(v);
                C[(size_t)m * Ncols + n] = v;
            }
}

// Weight transpose + hi/lo split: W [K,N] fp32 -> Wt [N, hi(K)|lo(K)] f16.
__global__ __launch_bounds__(256) void wsplit_kernel(const float* __restrict__ W,
                                                     f16* __restrict__ Wt,
                                                     int K, int N)
{
    __shared__ float tile[64][65];
    const int t = threadIdx.x;
    const int kb = blockIdx.y * 64, nb = blockIdx.x * 64;
    #pragma unroll
    for (int i = 0; i < 4; ++i) {
        int r = (t >> 4) + i * 16;
        int c = (t & 15) * 4;
        *(float4*)&tile[r][c] = *(const float4*)&W[(size_t)(kb + r) * N + nb + c];
    }
    __syncthreads();
    const int r2 = t >> 2;           // output row (n) within tile
    const int kc = (t & 3) * 16;     // k offset within tile
    f16x8 h0, h1, lo0, lo1;
    #pragma unroll
    for (int e = 0; e < 8; ++e) {
        float x = tile[kc + e][r2];
        f16 hh = (f16)x; h0[e] = hh; lo0[e] = (f16)(x - (float)hh);
        float y = tile[kc + 8 + e][r2];
        f16 hh2 = (f16)y; h1[e] = hh2; lo1[e] = (f16)(y - (float)hh2);
    }
    f16* base = Wt + (size_t)(nb + r2) * 2 * K + kb + kc;
    *(f16x8*)base = h0; *(f16x8*)(base + 8) = h1;
    *(f16x8*)(base + K) = lo0; *(f16x8*)(base + K + 8) = lo1;
}

// b_comb[n] = sum_k b_dim[k] * W_fus[512+k][n] + b_fus[n]
__global__ __launch_bounds__(256) void bcomb_kernel(const float* __restrict__ b_dim,
                                                    const float* __restrict__ W_fus2,
                                                    const float* __restrict__ b_fus,
                                                    float* __restrict__ b_comb)
{
    int n = blockIdx.x * 256 + threadIdx.x;
    if (n >= DDIM) return;
    float s = b_fus[n];
    for (int k = 0; k < DDIM; ++k) s += b_dim[k] * W_fus2[(size_t)k * DDIM + n];
    b_comb[n] = s;
}

// top-5 scan over one score chunk; persistent state in ws. One wave per src row.
// Pre-filters each float4 against min(global 5th-best, lane 5th-best): exact,
// since ids ascend (ties lose) and any final-top-5 key is in its lane's stream-top-5.
__global__ __launch_bounds__(256) void topk_scan_kernel(
    const float* __restrict__ g, const float* __restrict__ norm_a,
    float* __restrict__ bk_state, int* __restrict__ bi_state, int m0)
{
    int row = blockIdx.x * 4 + (threadIdx.x >> 6);
    int lane = threadIdx.x & 63;
    float bk[KNN]; int bi[KNN];
    #pragma unroll
    for (int q = 0; q < KNN; ++q) { bk[q] = 3.0e38f; bi[q] = 0x7fffffff; }
    const float gthr = bk_state[row * KNN + 4];   // row's global 5th-best so far

    const float* grow = g + (size_t)row * MCHUNK;
    #pragma unroll
    for (int it = 0; it < MCHUNK / 256; ++it) {
        int col = it * 256 + lane * 4;
        float4 gv = *(const float4*)(grow + col);
        float4 nv = *(const float4*)(norm_a + m0 + col);
        float k0 = nv.x - 2.f * gv.x;
        float k1 = nv.y - 2.f * gv.y;
        float k2 = nv.z - 2.f * gv.z;
        float k3 = nv.w - 2.f * gv.w;
        float kmin = fminf(fminf(k0, k1), fminf(k2, k3));
        float thr = fminf(gthr, bk[4]);
        if (kmin < thr) {
            insert5(bk, bi, k0, m0 + col);
            insert5(bk, bi, k1, m0 + col + 1);
            insert5(bk, bi, k2, m0 + col + 2);
            insert5(bk, bi, k3, m0 + col + 3);
        }
    }
    for (int off = 32; off >= 1; off >>= 1) {
        float ok[KNN]; int oi[KNN];
        #pragma unroll
        for (int q = 0; q < KNN; ++q) {
            ok[q] = __shfl_xor(bk[q], off, 64);
            oi[q] = __shfl_xor(bi[q], off, 64);
        }
        #pragma unroll
        for (int q = 0; q < KNN; ++q) insert5(bk, bi, ok[q], oi[q]);
    }
    if (lane == 0) {
        #pragma unroll
        for (int q = 0; q < KNN; ++q)
            insert5(bk, bi, bk_state[row * KNN + q], bi_state[row * KNN + q]);
        #pragma unroll
        for (int q = 0; q < KNN; ++q) {
            bk_state[row * KNN + q] = bk[q];
            bi_state[row * KNN + q] = bi[q];
        }
    }
}

__global__ __launch_bounds__(256) void gather_mean_kernel(
    const float* __restrict__ anchor, const int* __restrict__ bi_state,
    float* __restrict__ neigh)
{
    int row = blockIdx.x * 4 + (threadIdx.x >> 6);
    int lane = threadIdx.x & 63;
    const int* bi = bi_state + row * KNN;
    int i0 = bi[0], i1 = bi[1], i2 = bi[2], i3 = bi[3], i4 = bi[4];
    const float4* a0 = (const float4*)(anchor + (size_t)i0 * DDIM);
    const float4* a1 = (const float4*)(anchor + (size_t)i1 * DDIM);
    const float4* a2 = (const float4*)(anchor + (size_t)i2 * DDIM);
    const float4* a3 = (const float4*)(anchor + (size_t)i3 * DDIM);
    const float4* a4 = (const float4*)(anchor + (size_t)i4 * DDIM);
    float4* np = (float4*)(neigh + (size_t)row * DDIM);
    #pragma unroll
    for (int p = 0; p < 2; ++p) {
        int c4 = lane + 64 * p;
        float4 v0 = a0[c4], v1 = a1[c4], v2 = a2[c4], v3 = a3[c4], v4 = a4[c4];
        float4 o;
        o.x = (v0.x + v1.x + v2.x + v3.x + v4.x) * 0.2f;
        o.y = (v0.y + v1.y + v2.y + v3.y + v4.y) * 0.2f;
        o.z = (v0.z + v1.z + v2.z + v3.z + v4.z) * 0.2f;
        o.w = (v0.w + v1.w + v2.w + v3.w + v4.w) * 0.2f;
        np[c4] = o;
    }
}

// fp32 GEMM (used only for the tiny W_comb2 = W_dim @ W_fus2 fold).
template<int ACT>
__global__ __launch_bounds__(256) void gemm_kernel(
    const float* __restrict__ A, int K1,
    const float* __restrict__ A2, int K2,
    const float* __restrict__ B, const float* __restrict__ bias,
    float* __restrict__ C, int Ncols)
{
    __shared__ float As[16][132];
    __shared__ float Bs[16][128];
    const int t = threadIdx.x;
    const int n0 = blockIdx.x * 128;
    const int m0 = blockIdx.y * 128;
    const int ty = t >> 4, tx = t & 15;
    const int K = K1 + K2;

    float acc[8][8];
    #pragma unroll
    for (int i = 0; i < 8; ++i)
        #pragma unroll
        for (int j = 0; j < 8; ++j) acc[i][j] = 0.f;

    const int ar = t >> 1;
    const int akc = (t & 1) * 8;
    const int bkr = t >> 4;
    const int bc = (t & 15) * 8;

    for (int k0 = 0; k0 < K; k0 += 16) {
        int kk = k0 + akc;
        float4 v0, v1;
        if (kk < K1) {
            const float* p = A + (size_t)(m0 + ar) * K1 + kk;
            v0 = *(const float4*)p; v1 = *(const float4*)(p + 4);
        } else {
            const float* p = A2 + (size_t)(m0 + ar) * K2 + (kk - K1);
            v0 = *(const float4*)p; v1 = *(const float4*)(p + 4);
        }
        const float* bp = B + (size_t)(k0 + bkr) * Ncols + n0 + bc;
        float4 w0 = *(const float4*)bp, w1 = *(const float4*)(bp + 4);
        __syncthreads();
        As[akc+0][ar] = v0.x; As[akc+1][ar] = v0.y; As[akc+2][ar] = v0.z; As[akc+3][ar] = v0.w;
        As[akc+4][ar] = v1.x; As[akc+5][ar] = v1.y; As[akc+6][ar] = v1.z; As[akc+7][ar] = v1.w;
        *(float4*)&Bs[bkr][bc] = w0; *(float4*)&Bs[bkr][bc + 4] = w1;
        __syncthreads();
        #pragma unroll
        for (int k = 0; k < 16; ++k) {
            float a[8], b[8];
            *(float4*)&a[0] = *(const float4*)&As[k][ty * 8];
            *(float4*)&a[4] = *(const float4*)&As[k][ty * 8 + 4];
            *(float4*)&b[0] = *(const float4*)&Bs[k][tx * 4];
            *(float4*)&b[4] = *(const float4*)&Bs[k][64 + tx * 4];
            #pragma unroll
            for (int i = 0; i < 8; ++i)
                #pragma unroll
                for (int j = 0; j < 8; ++j) acc[i][j] += a[i] * b[j];
        }
    }
    float4 bv0 = *(const float4*)(bias + n0 + tx * 4);
    float4 bv1 = *(const float4*)(bias + n0 + 64 + tx * 4);
    #pragma unroll
    for (int i = 0; i < 8; ++i) {
        int row = m0 + ty * 8 + i;
        float4 o0, o1;
        o0.x = acc[i][0] + bv0.x; o0.y = acc[i][1] + bv0.y;
        o0.z = acc[i][2] + bv0.z; o0.w = acc[i][3] + bv0.w;
        o1.x = acc[i][4] + bv1.x; o1.y = acc[i][5] + bv1.y;
        o1.z = acc[i][6] + bv1.z; o1.w = acc[i][7] + bv1.w;
        if (ACT == 1) {
            o0.x = tanhf(o0.x); o0.y = tanhf(o0.y); o0.z = tanhf(o0.z); o0.w = tanhf(o0.w);
            o1.x = tanhf(o1.x); o1.y = tanhf(o1.y); o1.z = tanhf(o1.z); o1.w = tanhf(o1.w);
        }
        *(float4*)(C + (size_t)row * Ncols + n0 + tx * 4) = o0;
        *(float4*)(C + (size_t)row * Ncols + n0 + 64 + tx * 4) = o1;
    }
}

__global__ __launch_bounds__(256) void bn_stats_kernel(const float* __restrict__ X,
                                                       float* __restrict__ sums)
{
    __shared__ float red[8][64];
    int lane = threadIdx.x & 63;
    int rl = threadIdx.x >> 6;
    int c = blockIdx.x * 64 + lane;
    int chunk = N_ROWS / gridDim.y;
    int rbeg = blockIdx.y * chunk;
    float s = 0.f, s2 = 0.f;
    for (int r = rbeg + rl; r < rbeg + chunk; r += 4) {
        float v = X[(size_t)r * DDIM + c];
        s += v; s2 += v * v;
    }
    red[rl][lane] = s; red[4 + rl][lane] = s2;
    __syncthreads();
    if (threadIdx.x < 64) {
        float ts = red[0][lane] + red[1][lane] + red[2][lane] + red[3][lane];
        float t2 = red[4][lane] + red[5][lane] + red[6][lane] + red[7][lane];
        atomicAdd(&sums[c], ts);
        atomicAdd(&sums[DDIM + c], t2);
    }
}

template<int TANH>
__global__ __launch_bounds__(256) void bn_apply_kernel(
    const float* __restrict__ X, float* __restrict__ Y,
    const float* __restrict__ sums, const float* __restrict__ g,
    const float* __restrict__ b, float invN)
{
    size_t i = (size_t)blockIdx.x * 256 + threadIdx.x;
    int cg = (int)(i % (DDIM / 4));
    int c = cg * 4;
    float4 x = ((const float4*)X)[i];
    float4 sm = *(const float4*)(sums + c);
    float4 sq = *(const float4*)(sums + DDIM + c);
    float4 gv = *(const float4*)(g + c);
    float4 bv = *(const float4*)(b + c);
    float m, var, rs;
    m = sm.x * invN; var = sq.x * invN - m * m; rs = rsqrtf(var + BN_EPS);
    x.x = (x.x - m) * rs * gv.x + bv.x;
    m = sm.y * invN; var = sq.y * invN - m * m; rs = rsqrtf(var + BN_EPS);
    x.y = (x.y - m) * rs * gv.y + bv.y;
    m = sm.z * invN; var = sq.z * invN - m * m; rs = rsqrtf(var + BN_EPS);
    x.z = (x.z - m) * rs * gv.z + bv.z;
    m = sm.w * invN; var = sq.w * invN - m * m; rs = rsqrtf(var + BN_EPS);
    x.w = (x.w - m) * rs * gv.w + bv.w;
    if (TANH) { x.x = tanhf(x.x); x.y = tanhf(x.y); x.z = tanhf(x.z); x.w = tanhf(x.w); }
    ((float4*)Y)[i] = x;
}

extern "C" void kernel_launch(void* const* d_in, const int* in_sizes, int n_in,
                              void* d_out, int out_size, void* d_ws, size_t ws_size,
                              hipStream_t stream)
{
    const float* src   = (const float*)d_in[0];
    const float* anc   = (const float*)d_in[1];
    const float* W_dim = (const float*)d_in[2];
    const float* b_dim = (const float*)d_in[3];
    const float* W_fus = (const float*)d_in[4];
    const float* b_fus = (const float*)d_in[5];
    const float* W_e1  = (const float*)d_in[6];
    const float* b_e1  = (const float*)d_in[7];
    const float* W_e2  = (const float*)d_in[8];
    const float* b_e2  = (const float*)d_in[9];
    const float* g1    = (const float*)d_in[10];
    const float* bt1   = (const float*)d_in[11];
    const float* g2    = (const float*)d_in[12];
    const float* bt2   = (const float*)d_in[13];
    const float* W_d   = (const float*)d_in[14];
    const float* b_d   = (const float*)d_in[15];
    const float* g_d   = (const float*)d_in[16];
    const float* bt_d  = (const float*)d_in[17];
    float* out = (float*)d_out;          // doubles as `comb`

    float* ws = (float*)d_ws;
    // Layout (floats), total 44,478,464 fl = 177.9 MB:
    //  [0)            score (dist) / h fp32 chunk (network)   16,777,216
    //  [16,777,216)   bufA: neigh -> enc2-out(t)               8,388,608
    //  [25,165,824)   dist: src2+anc2 f16  |  network: weight f16 overlay
    //  [44,040,192)   W_comb2 fp32 262,144
    //  [44,302,336)   norm_a 8192 | sums 3072 | zeros 512 | b_comb 512 | bk/bi
    float* score  = ws;
    float* bufA   = ws + 16777216;
    f16*   src2   = (f16*)(ws + 25165824);     // 16384 x 1536 f16
    f16*   anc2   = (f16*)(ws + 37748736);     // 8192 x 1536 f16
    f16*   wbase  = (f16*)(ws + 25165824);     // weight overlay (after dist)
    f16*   Wt_fus1  = wbase;                   // [512, 1024]
    f16*   Wt_comb2 = wbase + 524288;          // [512, 1024]
    f16*   Wt_e1    = wbase + 1048576;         // [2048, 1024]
    f16*   Wt_e2    = wbase + 3145728;         // [512, 4096]
    f16*   Wt_d     = wbase + 5242880;         // [512, 1024]
    float* W_comb2  = ws + 44040192;
    float* norm_a   = ws + 44302336;
    float* sums1    = ws + 44310528;
    float* sums2    = sums1 + 1024;
    float* sums3    = sums2 + 1024;
    float* zeros512 = ws + 44313600;
    float* b_comb   = ws + 44314112;
    float* bk_state = ws + 44314624;
    int*   bi_state = (int*)(ws + 44396544);

    const float invN = 1.0f / (float)N_ROWS;
    float* hbuf = score;   // network-phase alias

    zero_kernel<<<dim3(14), 256, 0, stream>>>(sums1, 3584);   // sums1..3 + zeros512
    init_state_kernel<<<dim3(320), 256, 0, stream>>>(bk_state, bi_state, N_ROWS * KNN);
    split_kernel<0><<<dim3(N_ROWS * DDIM / 1024), 256, 0, stream>>>(src, src2, N_ROWS);
    split_kernel<1><<<dim3(M_ANCH * DDIM / 1024), 256, 0, stream>>>(anc, anc2, M_ANCH);
    anchor_norm_kernel<<<dim3(M_ANCH / 4), 256, 0, stream>>>(anc, norm_a);

    // dist: 8 anchor chunks: MFMA GEMM -> score -> top-5 scan
    for (int m0 = 0; m0 < M_ANCH; m0 += MCHUNK) {
        gemm_f16_nt<<<dim3(MCHUNK / 128, N_ROWS / 128), 256, 0, stream>>>(
            src2, anc2 + (size_t)m0 * KSPLIT, score, KSPLIT, MCHUNK);
        topk_scan_kernel<<<dim3(N_ROWS / 4), 256, 0, stream>>>(
            score, norm_a, bk_state, bi_state, m0);
    }
    gather_mean_kernel<<<dim3(N_ROWS / 4), 256, 0, stream>>>(anc, bi_state, bufA);

    // Weight prep (overlays dead src2/anc2 region)
    wsplit_kernel<<<dim3(DDIM / 64, DDIM / 64), 256, 0, stream>>>(W_fus, Wt_fus1, DDIM, DDIM);
    wsplit_kernel<<<dim3(FDIM / 64, DDIM / 64), 256, 0, stream>>>(W_e1, Wt_e1, DDIM, FDIM);
    wsplit_kernel<<<dim3(DDIM / 64, FDIM / 64), 256, 0, stream>>>(W_e2, Wt_e2, FDIM, DDIM);
    wsplit_kernel<<<dim3(DDIM / 64, DDIM / 64), 256, 0, stream>>>(W_d, Wt_d, DDIM, DDIM);
    // W_comb2 = W_dim @ W_fus[512:,:]; b_comb = b_dim @ W_fus[512:,:] + b_fus
    gemm_kernel<0><<<dim3(4, 4), 256, 0, stream>>>(
        W_dim, DDIM, nullptr, 0, W_fus + DDIM * DDIM, zeros512, W_comb2, DDIM);
    bcomb_kernel<<<dim3(2), 256, 0, stream>>>(b_dim, W_fus + DDIM * DDIM, b_fus, b_comb);
    wsplit_kernel<<<dim3(DDIM / 64, DDIM / 64), 256, 0, stream>>>(W_comb2, Wt_comb2, DDIM, DDIM);

    // comb = src @ Wf1 + b_comb + neigh @ W_comb2   -> out, then BN1
    gemm_split_nt<0, 0><<<dim3(DDIM / 128, N_ROWS / 128), 256, 0, stream>>>(
        src, Wt_fus1, b_comb, nullptr, out, DDIM, DDIM);
    gemm_split_nt<1, 0><<<dim3(DDIM / 128, N_ROWS / 128), 256, 0, stream>>>(
        bufA, Wt_comb2, nullptr, out, out, DDIM, DDIM);
    bn_stats_kernel<<<dim3(DDIM / 64, 16), 256, 0, stream>>>(out, sums1);
    bn_apply_kernel<0><<<dim3(8192), 256, 0, stream>>>(out, out, sums1, g1, bt1, invN);

    // encoder, chunked: h = tanh(comb@We1+b1); t = h@We2 + b2 + comb
    for (int r0 = 0; r0 < N_ROWS; r0 += CHUNK) {
        gemm_split_nt<0, 1><<<dim3(FDIM / 128, CHUNK / 128), 256, 0, stream>>>(
            out + (size_t)r0 * DDIM, Wt_e1, b_e1, nullptr, hbuf, DDIM, FDIM);
        gemm_split_nt<1, 0><<<dim3(DDIM / 128, CHUNK / 128), 256, 0, stream>>>(
            hbuf, Wt_e2, b_e2, out + (size_t)r0 * DDIM, bufA + (size_t)r0 * DDIM,
            FDIM, DDIM);
    }
    bn_stats_kernel<<<dim3(DDIM / 64, 16), 256, 0, stream>>>(bufA, sums2);
    bn_apply_kernel<0><<<dim3(8192), 256, 0, stream>>>(bufA, bufA, sums2, g2, bt2, invN);

    // decoder -> out, BN3 + tanh
    gemm_split_nt<0, 0><<<dim3(DDIM / 128, N_ROWS / 128), 256, 0, stream>>>(
        bufA, Wt_d, b_d, nullptr, out, DDIM, DDIM);
    bn_stats_kernel<<<dim3(DDIM / 64, 16), 256, 0, stream>>>(out, sums3);
    bn_apply_kernel<1><<<dim3(8192), 256, 0, stream>>>(out, out, sums3, g_d, bt_d, invN);
}

// Round 6
// 1901.870 us; speedup vs baseline: 2.4493x; 1.4710x over previous
//
#include <hip/hip_runtime.h>
#include <math.h>

#define N_ROWS 16384
#define M_ANCH 8192
#define DDIM   512
#define FDIM   2048
#define KNN    5
#define BN_EPS 1e-5f
#define CHUNK  8192    // network-phase row chunk (h fp32 chunk = 64 MB, in score region)
#define SEED   1024    // dist seed chunk (exact scan); rest via candidate collection
#define KSPLIT 1536    // 3 x 512 virtual-K for dist hi/lo split product
#define CAND_MAX 256   // per-row candidate buffer (E[count]~35, P(overflow)~4e-10)

typedef _Float16 f16;
typedef _Float16 f16x8 __attribute__((ext_vector_type(8)));
typedef _Float16 f16x4 __attribute__((ext_vector_type(4)));
typedef float f32x4 __attribute__((ext_vector_type(4)));

__device__ __forceinline__ void async_copy16(const void* g, void* l) {
    __builtin_amdgcn_global_load_lds(
        (const __attribute__((address_space(1))) void*)g,
        (__attribute__((address_space(3))) void*)l, 16, 0, 0);
}

__device__ __forceinline__ bool kless(float k1, int i1, float k2, int i2) {
    return (k1 < k2) || (k1 == k2 && i1 < i2);
}

__device__ __forceinline__ void insert5(float (&bk)[KNN], int (&bi)[KNN], float key, int id) {
    if (!kless(key, id, bk[4], bi[4])) return;
    bool c3 = kless(key, id, bk[3], bi[3]);
    bool c2 = kless(key, id, bk[2], bi[2]);
    bool c1 = kless(key, id, bk[1], bi[1]);
    bool c0 = kless(key, id, bk[0], bi[0]);
    bk[4] = c3 ? bk[3] : key;                  bi[4] = c3 ? bi[3] : id;
    bk[3] = c3 ? (c2 ? bk[2] : key) : bk[3];   bi[3] = c3 ? (c2 ? bi[2] : id) : bi[3];
    bk[2] = c2 ? (c1 ? bk[1] : key) : bk[2];   bi[2] = c2 ? (c1 ? bi[1] : id) : bi[2];
    bk[1] = c1 ? (c0 ? bk[0] : key) : bk[1];   bi[1] = c1 ? (c0 ? bi[0] : id) : bi[1];
    bk[0] = c0 ? key : bk[0];                  bi[0] = c0 ? id : bi[0];
}

__global__ void zero_kernel(float* p, int n) {
    int i = blockIdx.x * blockDim.x + threadIdx.x;
    if (i < n) p[i] = 0.f;
}

__global__ void init_state_kernel(float* bk, int* bi, int n) {
    int i = blockIdx.x * blockDim.x + threadIdx.x;
    if (i < n) { bk[i] = 3.0e38f; bi[i] = 0x7fffffff; }
}

// fp32 -> f16 hi/lo split into virtual-K layout (dist phase).
// MODE 0 (src): segs [hi | lo | hi];  MODE 1 (anchor): segs [hi | hi | lo]
template<int MODE>
__global__ __launch_bounds__(256) void split_kernel(const float* __restrict__ X,
                                                    f16* __restrict__ Y, int nrows) {
    int i4 = blockIdx.x * 256 + threadIdx.x;
    int row = i4 >> 7;
    int kc = (i4 & 127) * 4;
    if (row >= nrows) return;
    float4 v = ((const float4*)X)[i4];
    f16x4 h, lo;
    h.x = (f16)v.x; h.y = (f16)v.y; h.z = (f16)v.z; h.w = (f16)v.w;
    lo.x = (f16)(v.x - (float)h.x); lo.y = (f16)(v.y - (float)h.y);
    lo.z = (f16)(v.z - (float)h.z); lo.w = (f16)(v.w - (float)h.w);
    f16* base = Y + (size_t)row * KSPLIT + kc;
    if (MODE == 0) {
        *(f16x4*)(base) = h; *(f16x4*)(base + 512) = lo; *(f16x4*)(base + 1024) = h;
    } else {
        *(f16x4*)(base) = h; *(f16x4*)(base + 512) = h;  *(f16x4*)(base + 1024) = lo;
    }
}

__global__ __launch_bounds__(256) void anchor_norm_kernel(const float* __restrict__ a,
                                                          float* __restrict__ norm_a) {
    int wave = threadIdx.x >> 6, lane = threadIdx.x & 63;
    int row = blockIdx.x * 4 + wave;
    const float4* ar = (const float4*)(a + (size_t)row * DDIM);
    float4 v1 = ar[lane * 2];
    float4 v2 = ar[lane * 2 + 1];
    float s = v1.x*v1.x + v1.y*v1.y + v1.z*v1.z + v1.w*v1.w
            + v2.x*v2.x + v2.y*v2.y + v2.z*v2.z + v2.w*v2.w;
    for (int off = 32; off; off >>= 1) s += __shfl_xor(s, off, 64);
    if (lane == 0) norm_a[row] = s;
}

// dist-phase f16 NT GEMM (pre-split operands): C[m][n] = sum_k A[m][k]*B[n][k].
// Used only for the seed chunk (writes score).
__global__ __launch_bounds__(256) void gemm_f16_nt(
    const f16* __restrict__ A, const f16* __restrict__ B,
    float* __restrict__ C, int K, int Ncols)
{
    __shared__ f16 As[128 * 32];
    __shared__ f16 Bs[128 * 32];
    const int t = threadIdx.x;
    const int w = t >> 6, l = t & 63;
    const int m0 = blockIdx.y * 128, n0 = blockIdx.x * 128;
    const int wm = (w & 1) * 64, wn = (w >> 1) * 64;

    f32x4 acc[4][4];
    #pragma unroll
    for (int i = 0; i < 4; ++i)
        #pragma unroll
        for (int j = 0; j < 4; ++j) acc[i][j] = (f32x4){0.f, 0.f, 0.f, 0.f};

    const int srow = l >> 2;
    const int skoff = (l & 3) * 8;

    for (int k0 = 0; k0 < K; k0 += 32) {
        __syncthreads();
        #pragma unroll
        for (int s = 0; s < 2; ++s) {
            int grp = w * 2 + s;
            int row = grp * 16 + srow;
            async_copy16(A + (size_t)(m0 + row) * K + k0 + skoff, As + grp * 512 + l * 8);
            async_copy16(B + (size_t)(n0 + row) * K + k0 + skoff, Bs + grp * 512 + l * 8);
        }
        __syncthreads();
        f16x8 af[4], bf[4];
        #pragma unroll
        for (int i = 0; i < 4; ++i)
            af[i] = *(const f16x8*)(As + (wm + i * 16 + (l & 15)) * 32 + (l >> 4) * 8);
        #pragma unroll
        for (int j = 0; j < 4; ++j)
            bf[j] = *(const f16x8*)(Bs + (wn + j * 16 + (l & 15)) * 32 + (l >> 4) * 8);
        #pragma unroll
        for (int i = 0; i < 4; ++i)
            #pragma unroll
            for (int j = 0; j < 4; ++j)
                acc[i][j] = __builtin_amdgcn_mfma_f32_16x16x32_f16(af[i], bf[j], acc[i][j], 0, 0, 0);
    }
    #pragma unroll
    for (int i = 0; i < 4; ++i)
        #pragma unroll
        for (int j = 0; j < 4; ++j)
            #pragma unroll
            for (int r = 0; r < 4; ++r) {
                int m = m0 + wm + i * 16 + (l >> 4) * 4 + r;
                int n = n0 + wn + j * 16 + (l & 15);
                C[(size_t)m * Ncols + n] = acc[i][j][r];
            }
}

// Collect GEMM for anchors [SEED..M): same MFMA core, but instead of writing C,
// computes key = norm[col] - 2*acc and appends (key, id) to per-row candidate
// lists when key < thr[row] (thr = seeded 5th-best; strict < is exact since
// all seed ids are smaller and ties lose by id).
__global__ __launch_bounds__(256) void gemm_collect(
    const f16* __restrict__ A, const f16* __restrict__ B,
    const float* __restrict__ norm,      // norm of B rows (pre-offset)
    const float* __restrict__ thr,       // [N_ROWS] per-row threshold
    int* __restrict__ cnt, float* __restrict__ cand_k, int* __restrict__ cand_i,
    int K, int idofs)
{
    __shared__ f16 As[128 * 32];
    __shared__ f16 Bs[128 * 32];
    const int t = threadIdx.x;
    const int w = t >> 6, l = t & 63;
    const int m0 = blockIdx.y * 128, n0 = blockIdx.x * 128;
    const int wm = (w & 1) * 64, wn = (w >> 1) * 64;

    f32x4 acc[4][4];
    #pragma unroll
    for (int i = 0; i < 4; ++i)
        #pragma unroll
        for (int j = 0; j < 4; ++j) acc[i][j] = (f32x4){0.f, 0.f, 0.f, 0.f};

    const int srow = l >> 2;
    const int skoff = (l & 3) * 8;

    for (int k0 = 0; k0 < K; k0 += 32) {
        __syncthreads();
        #pragma unroll
        for (int s = 0; s < 2; ++s) {
            int grp = w * 2 + s;
            int row = grp * 16 + srow;
            async_copy16(A + (size_t)(m0 + row) * K + k0 + skoff, As + grp * 512 + l * 8);
            async_copy16(B + (size_t)(n0 + row) * K + k0 + skoff, Bs + grp * 512 + l * 8);
        }
        __syncthreads();
        f16x8 af[4], bf[4];
        #pragma unroll
        for (int i = 0; i < 4; ++i)
            af[i] = *(const f16x8*)(As + (wm + i * 16 + (l & 15)) * 32 + (l >> 4) * 8);
        #pragma unroll
        for (int j = 0; j < 4; ++j)
            bf[j] = *(const f16x8*)(Bs + (wn + j * 16 + (l & 15)) * 32 + (l >> 4) * 8);
        #pragma unroll
        for (int i = 0; i < 4; ++i)
            #pragma unroll
            for (int j = 0; j < 4; ++j)
                acc[i][j] = __builtin_amdgcn_mfma_f32_16x16x32_f16(af[i], bf[j], acc[i][j], 0, 0, 0);
    }
    // epilogue: threshold test + rare append
    float thr4[4][4];
    #pragma unroll
    for (int i = 0; i < 4; ++i) {
        float4 tv = *(const float4*)&thr[m0 + wm + i * 16 + (l >> 4) * 4];
        thr4[i][0] = tv.x; thr4[i][1] = tv.y; thr4[i][2] = tv.z; thr4[i][3] = tv.w;
    }
    float nj[4];
    #pragma unroll
    for (int j = 0; j < 4; ++j) nj[j] = norm[n0 + wn + j * 16 + (l & 15)];
    #pragma unroll
    for (int i = 0; i < 4; ++i)
        #pragma unroll
        for (int j = 0; j < 4; ++j)
            #pragma unroll
            for (int r = 0; r < 4; ++r) {
                float key = nj[j] - 2.f * acc[i][j][r];
                if (key < thr4[i][r]) {
                    int row = m0 + wm + i * 16 + (l >> 4) * 4 + r;
                    int pos = atomicAdd(&cnt[row], 1);
                    if (pos < CAND_MAX) {
                        cand_k[(size_t)row * CAND_MAX + pos] = key;
                        cand_i[(size_t)row * CAND_MAX + pos] =
                            idofs + n0 + wn + j * 16 + (l & 15);
                    }
                }
            }
}

// exact top-5 scan over the seed score chunk; also writes thrbuf = 5th-best.
__global__ __launch_bounds__(256) void topk_scan_kernel(
    const float* __restrict__ g, const float* __restrict__ norm_a,
    float* __restrict__ bk_state, int* __restrict__ bi_state,
    float* __restrict__ thrbuf, int m0)
{
    int row = blockIdx.x * 4 + (threadIdx.x >> 6);
    int lane = threadIdx.x & 63;
    float bk[KNN]; int bi[KNN];
    #pragma unroll
    for (int q = 0; q < KNN; ++q) { bk[q] = 3.0e38f; bi[q] = 0x7fffffff; }

    const float* grow = g + (size_t)row * SEED;
    #pragma unroll
    for (int it = 0; it < SEED / 256; ++it) {
        int col = it * 256 + lane * 4;
        float4 gv = *(const float4*)(grow + col);
        float4 nv = *(const float4*)(norm_a + m0 + col);
        float k0 = nv.x - 2.f * gv.x;
        float k1 = nv.y - 2.f * gv.y;
        float k2 = nv.z - 2.f * gv.z;
        float k3 = nv.w - 2.f * gv.w;
        float kmin = fminf(fminf(k0, k1), fminf(k2, k3));
        if (kmin < bk[4]) {
            insert5(bk, bi, k0, m0 + col);
            insert5(bk, bi, k1, m0 + col + 1);
            insert5(bk, bi, k2, m0 + col + 2);
            insert5(bk, bi, k3, m0 + col + 3);
        }
    }
    for (int off = 32; off >= 1; off >>= 1) {
        float ok[KNN]; int oi[KNN];
        #pragma unroll
        for (int q = 0; q < KNN; ++q) {
            ok[q] = __shfl_xor(bk[q], off, 64);
            oi[q] = __shfl_xor(bi[q], off, 64);
        }
        #pragma unroll
        for (int q = 0; q < KNN; ++q) insert5(bk, bi, ok[q], oi[q]);
    }
    if (lane == 0) {
        #pragma unroll
        for (int q = 0; q < KNN; ++q) {
            bk_state[row * KNN + q] = bk[q];
            bi_state[row * KNN + q] = bi[q];
        }
        thrbuf[row] = bk[4];
    }
}

// merge collected candidates into seeded top-5; writes final indices.
__global__ __launch_bounds__(256) void cand_merge_kernel(
    const int* __restrict__ cnt, const float* __restrict__ cand_k,
    const int* __restrict__ cand_i, float* __restrict__ bk_state,
    int* __restrict__ bi_state)
{
    int row = blockIdx.x * 256 + threadIdx.x;
    if (row >= N_ROWS) return;
    float bk[KNN]; int bi[KNN];
    #pragma unroll
    for (int q = 0; q < KNN; ++q) {
        bk[q] = bk_state[row * KNN + q];
        bi[q] = bi_state[row * KNN + q];
    }
    int c = cnt[row]; if (c > CAND_MAX) c = CAND_MAX;
    const float* ck = cand_k + (size_t)row * CAND_MAX;
    const int*   ci = cand_i + (size_t)row * CAND_MAX;
    for (int p = 0; p < c; ++p) insert5(bk, bi, ck[p], ci[p]);
    #pragma unroll
    for (int q = 0; q < KNN; ++q) bi_state[row * KNN + q] = bi[q];
}

__global__ __launch_bounds__(256) void gather_mean_kernel(
    const float* __restrict__ anchor, const int* __restrict__ bi_state,
    float* __restrict__ neigh)
{
    int row = blockIdx.x * 4 + (threadIdx.x >> 6);
    int lane = threadIdx.x & 63;
    const int* bi = bi_state + row * KNN;
    int i0 = bi[0], i1 = bi[1], i2 = bi[2], i3 = bi[3], i4 = bi[4];
    const float4* a0 = (const float4*)(anchor + (size_t)i0 * DDIM);
    const float4* a1 = (const float4*)(anchor + (size_t)i1 * DDIM);
    const float4* a2 = (const float4*)(anchor + (size_t)i2 * DDIM);
    const float4* a3 = (const float4*)(anchor + (size_t)i3 * DDIM);
    const float4* a4 = (const float4*)(anchor + (size_t)i4 * DDIM);
    float4* np = (float4*)(neigh + (size_t)row * DDIM);
    #pragma unroll
    for (int p = 0; p < 2; ++p) {
        int c4 = lane + 64 * p;
        float4 v0 = a0[c4], v1 = a1[c4], v2 = a2[c4], v3 = a3[c4], v4 = a4[c4];
        float4 o;
        o.x = (v0.x + v1.x + v2.x + v3.x + v4.x) * 0.2f;
        o.y = (v0.y + v1.y + v2.y + v3.y + v4.y) * 0.2f;
        o.z = (v0.z + v1.z + v2.z + v3.z + v4.z) * 0.2f;
        o.w = (v0.w + v1.w + v2.w + v3.w + v4.w) * 0.2f;
        np[c4] = o;
    }
}

// Network GEMM: C = act(A @ BwT + bias [+ C0]).  A fp32 [M,K] split in-kernel to
// f16 hi/lo LDS tiles; Bw pre-split f16 [N, hi(K)|lo(K)].  3-term product -> fp32-grade.
template<int ADDC0, int TANH>
__global__ __launch_bounds__(256) void gemm_split_nt(
    const float* __restrict__ A, const f16* __restrict__ Bw,
    const float* __restrict__ bias, const float* __restrict__ C0,
    float* __restrict__ C, int K, int Ncols)
{
    __shared__ f16 Ah[128 * 32];
    __shared__ f16 Al[128 * 32];
    __shared__ f16 Bh[128 * 32];
    __shared__ f16 Bl[128 * 32];
    const int t = threadIdx.x;
    const int w = t >> 6, l = t & 63;
    const int m0 = blockIdx.y * 128, n0 = blockIdx.x * 128;
    const int wm = (w & 1) * 64, wn = (w >> 1) * 64;
    const int K2 = 2 * K;

    f32x4 acc[4][4];
    #pragma unroll
    for (int i = 0; i < 4; ++i)
        #pragma unroll
        for (int j = 0; j < 4; ++j) acc[i][j] = (f32x4){0.f, 0.f, 0.f, 0.f};

    const int ar = t >> 1;
    const int ac = (t & 1) * 16;
    const int srow = l >> 2;
    const int skoff = (l & 3) * 8;

    for (int k0 = 0; k0 < K; k0 += 32) {
        __syncthreads();
        #pragma unroll
        for (int s = 0; s < 2; ++s) {
            int grp = w * 2 + s;
            int row = grp * 16 + srow;
            const f16* bp = Bw + (size_t)(n0 + row) * K2 + k0 + skoff;
            async_copy16(bp, Bh + grp * 512 + l * 8);
            async_copy16(bp + K, Bl + grp * 512 + l * 8);
        }
        {
            const float* ap = A + (size_t)(m0 + ar) * K + k0 + ac;
            float xs[16];
            *(float4*)&xs[0]  = *(const float4*)ap;
            *(float4*)&xs[4]  = *(const float4*)(ap + 4);
            *(float4*)&xs[8]  = *(const float4*)(ap + 8);
            *(float4*)&xs[12] = *(const float4*)(ap + 12);
            f16x8 h0, h1, lo0, lo1;
            #pragma unroll
            for (int e = 0; e < 8; ++e) {
                f16 hh = (f16)xs[e];
                h0[e] = hh; lo0[e] = (f16)(xs[e] - (float)hh);
                f16 hh2 = (f16)xs[8 + e];
                h1[e] = hh2; lo1[e] = (f16)(xs[8 + e] - (float)hh2);
            }
            *(f16x8*)&Ah[ar * 32 + ac] = h0;  *(f16x8*)&Ah[ar * 32 + ac + 8] = h1;
            *(f16x8*)&Al[ar * 32 + ac] = lo0; *(f16x8*)&Al[ar * 32 + ac + 8] = lo1;
        }
        __syncthreads();
        f16x8 afh[4], afl[4], bfh[4], bfl[4];
        #pragma unroll
        for (int i = 0; i < 4; ++i) {
            int base = (wm + i * 16 + (l & 15)) * 32 + (l >> 4) * 8;
            afh[i] = *(const f16x8*)(Ah + base);
            afl[i] = *(const f16x8*)(Al + base);
        }
        #pragma unroll
        for (int j = 0; j < 4; ++j) {
            int base = (wn + j * 16 + (l & 15)) * 32 + (l >> 4) * 8;
            bfh[j] = *(const f16x8*)(Bh + base);
            bfl[j] = *(const f16x8*)(Bl + base);
        }
        #pragma unroll
        for (int i = 0; i < 4; ++i)
            #pragma unroll
            for (int j = 0; j < 4; ++j) {
                acc[i][j] = __builtin_amdgcn_mfma_f32_16x16x32_f16(afh[i], bfh[j], acc[i][j], 0, 0, 0);
                acc[i][j] = __builtin_amdgcn_mfma_f32_16x16x32_f16(afl[i], bfh[j], acc[i][j], 0, 0, 0);
                acc[i][j] = __builtin_amdgcn_mfma_f32_16x16x32_f16(afh[i], bfl[j], acc[i][j], 0, 0, 0);
            }
    }
    float bv[4];
    #pragma unroll
    for (int j = 0; j < 4; ++j)
        bv[j] = bias ? bias[n0 + wn + j * 16 + (l & 15)] : 0.f;
    #pragma unroll
    for (int i = 0; i < 4; ++i)
        #pragma unroll
        for (int j = 0; j < 4; ++j)
            #pragma unroll
            for (int r = 0; r < 4; ++r) {
                int m = m0 + wm + i * 16 + (l >> 4) * 4 + r;
                int n = n0 + wn + j * 16 + (l & 15);
                float v = acc[i][j][r] + bv[j];
                if (ADDC0) v += C0[(size_t)m * Ncols + n];
                if (TANH)  v = tanhf(v);
                C[(size_t)m * Ncols + n] = v;
            }
}

// Weight transpose + hi/lo split: W [K,N] fp32 -> Wt [N, hi(K)|lo(K)] f16.
__global__ __launch_bounds__(256) void wsplit_kernel(const float* __restrict__ W,
                                                     f16* __restrict__ Wt,
                                                     int K, int N)
{
    __shared__ float tile[64][65];
    const int t = threadIdx.x;
    const int kb = blockIdx.y * 64, nb = blockIdx.x * 64;
    #pragma unroll
    for (int i = 0; i < 4; ++i) {
        int r = (t >> 4) + i * 16;
        int c = (t & 15) * 4;
        *(float4*)&tile[r][c] = *(const float4*)&W[(size_t)(kb + r) * N + nb + c];
    }
    __syncthreads();
    const int r2 = t >> 2;
    const int kc = (t & 3) * 16;
    f16x8 h0, h1, lo0, lo1;
    #pragma unroll
    for (int e = 0; e < 8; ++e) {
        float x = tile[kc + e][r2];
        f16 hh = (f16)x; h0[e] = hh; lo0[e] = (f16)(x - (float)hh);
        float y = tile[kc + 8 + e][r2];
        f16 hh2 = (f16)y; h1[e] = hh2; lo1[e] = (f16)(y - (float)hh2);
    }
    f16* base = Wt + (size_t)(nb + r2) * 2 * K + kb + kc;
    *(f16x8*)base = h0; *(f16x8*)(base + 8) = h1;
    *(f16x8*)(base + K) = lo0; *(f16x8*)(base + K + 8) = lo1;
}

// b_comb[n] = sum_k b_dim[k] * W_fus[512+k][n] + b_fus[n]
__global__ __launch_bounds__(256) void bcomb_kernel(const float* __restrict__ b_dim,
                                                    const float* __restrict__ W_fus2,
                                                    const float* __restrict__ b_fus,
                                                    float* __restrict__ b_comb)
{
    int n = blockIdx.x * 256 + threadIdx.x;
    if (n >= DDIM) return;
    float s = b_fus[n];
    for (int k = 0; k < DDIM; ++k) s += b_dim[k] * W_fus2[(size_t)k * DDIM + n];
    b_comb[n] = s;
}

// fp32 GEMM (used only for the tiny W_comb2 = W_dim @ W_fus2 fold).
template<int ACT>
__global__ __launch_bounds__(256) void gemm_kernel(
    const float* __restrict__ A, int K1,
    const float* __restrict__ A2, int K2,
    const float* __restrict__ B, const float* __restrict__ bias,
    float* __restrict__ C, int Ncols)
{
    __shared__ float As[16][132];
    __shared__ float Bs[16][128];
    const int t = threadIdx.x;
    const int n0 = blockIdx.x * 128;
    const int m0 = blockIdx.y * 128;
    const int ty = t >> 4, tx = t & 15;
    const int K = K1 + K2;

    float acc[8][8];
    #pragma unroll
    for (int i = 0; i < 8; ++i)
        #pragma unroll
        for (int j = 0; j < 8; ++j) acc[i][j] = 0.f;

    const int ar = t >> 1;
    const int akc = (t & 1) * 8;
    const int bkr = t >> 4;
    const int bc = (t & 15) * 8;

    for (int k0 = 0; k0 < K; k0 += 16) {
        int kk = k0 + akc;
        float4 v0, v1;
        if (kk < K1) {
            const float* p = A + (size_t)(m0 + ar) * K1 + kk;
            v0 = *(const float4*)p; v1 = *(const float4*)(p + 4);
        } else {
            const float* p = A2 + (size_t)(m0 + ar) * K2 + (kk - K1);
            v0 = *(const float4*)p; v1 = *(const float4*)(p + 4);
        }
        const float* bp = B + (size_t)(k0 + bkr) * Ncols + n0 + bc;
        float4 w0 = *(const float4*)bp, w1 = *(const float4*)(bp + 4);
        __syncthreads();
        As[akc+0][ar] = v0.x; As[akc+1][ar] = v0.y; As[akc+2][ar] = v0.z; As[akc+3][ar] = v0.w;
        As[akc+4][ar] = v1.x; As[akc+5][ar] = v1.y; As[akc+6][ar] = v1.z; As[akc+7][ar] = v1.w;
        *(float4*)&Bs[bkr][bc] = w0; *(float4*)&Bs[bkr][bc + 4] = w1;
        __syncthreads();
        #pragma unroll
        for (int k = 0; k < 16; ++k) {
            float a[8], b[8];
            *(float4*)&a[0] = *(const float4*)&As[k][ty * 8];
            *(float4*)&a[4] = *(const float4*)&As[k][ty * 8 + 4];
            *(float4*)&b[0] = *(const float4*)&Bs[k][tx * 4];
            *(float4*)&b[4] = *(const float4*)&Bs[k][64 + tx * 4];
            #pragma unroll
            for (int i = 0; i < 8; ++i)
                #pragma unroll
                for (int j = 0; j < 8; ++j) acc[i][j] += a[i] * b[j];
        }
    }
    float4 bv0 = *(const float4*)(bias + n0 + tx * 4);
    float4 bv1 = *(const float4*)(bias + n0 + 64 + tx * 4);
    #pragma unroll
    for (int i = 0; i < 8; ++i) {
        int row = m0 + ty * 8 + i;
        float4 o0, o1;
        o0.x = acc[i][0] + bv0.x; o0.y = acc[i][1] + bv0.y;
        o0.z = acc[i][2] + bv0.z; o0.w = acc[i][3] + bv0.w;
        o1.x = acc[i][4] + bv1.x; o1.y = acc[i][5] + bv1.y;
        o1.z = acc[i][6] + bv1.z; o1.w = acc[i][7] + bv1.w;
        if (ACT == 1) {
            o0.x = tanhf(o0.x); o0.y = tanhf(o0.y); o0.z = tanhf(o0.z); o0.w = tanhf(o0.w);
            o1.x = tanhf(o1.x); o1.y = tanhf(o1.y); o1.z = tanhf(o1.z); o1.w = tanhf(o1.w);
        }
        *(float4*)(C + (size_t)row * Ncols + n0 + tx * 4) = o0;
        *(float4*)(C + (size_t)row * Ncols + n0 + 64 + tx * 4) = o1;
    }
}

__global__ __launch_bounds__(256) void bn_stats_kernel(const float* __restrict__ X,
                                                       float* __restrict__ sums)
{
    __shared__ float red[8][64];
    int lane = threadIdx.x & 63;
    int rl = threadIdx.x >> 6;
    int c = blockIdx.x * 64 + lane;
    int chunk = N_ROWS / gridDim.y;
    int rbeg = blockIdx.y * chunk;
    float s = 0.f, s2 = 0.f;
    for (int r = rbeg + rl; r < rbeg + chunk; r += 4) {
        float v = X[(size_t)r * DDIM + c];
        s += v; s2 += v * v;
    }
    red[rl][lane] = s; red[4 + rl][lane] = s2;
    __syncthreads();
    if (threadIdx.x < 64) {
        float ts = red[0][lane] + red[1][lane] + red[2][lane] + red[3][lane];
        float t2 = red[4][lane] + red[5][lane] + red[6][lane] + red[7][lane];
        atomicAdd(&sums[c], ts);
        atomicAdd(&sums[DDIM + c], t2);
    }
}

template<int TANH>
__global__ __launch_bounds__(256) void bn_apply_kernel(
    const float* __restrict__ X, float* __restrict__ Y,
    const float* __restrict__ sums, const float* __restrict__ g,
    const float* __restrict__ b, float invN)
{
    size_t i = (size_t)blockIdx.x * 256 + threadIdx.x;
    int cg = (int)(i % (DDIM / 4));
    int c = cg * 4;
    float4 x = ((const float4*)X)[i];
    float4 sm = *(const float4*)(sums + c);
    float4 sq = *(const float4*)(sums + DDIM + c);
    float4 gv = *(const float4*)(g + c);
    float4 bv = *(const float4*)(b + c);
    float m, var, rs;
    m = sm.x * invN; var = sq.x * invN - m * m; rs = rsqrtf(var + BN_EPS);
    x.x = (x.x - m) * rs * gv.x + bv.x;
    m = sm.y * invN; var = sq.y * invN - m * m; rs = rsqrtf(var + BN_EPS);
    x.y = (x.y - m) * rs * gv.y + bv.y;
    m = sm.z * invN; var = sq.z * invN - m * m; rs = rsqrtf(var + BN_EPS);
    x.z = (x.z - m) * rs * gv.z + bv.z;
    m = sm.w * invN; var = sq.w * invN - m * m; rs = rsqrtf(var + BN_EPS);
    x.w = (x.w - m) * rs * gv.w + bv.w;
    if (TANH) { x.x = tanhf(x.x); x.y = tanhf(x.y); x.z = tanhf(x.z); x.w = tanhf(x.w); }
    ((float4*)Y)[i] = x;
}

extern "C" void kernel_launch(void* const* d_in, const int* in_sizes, int n_in,
                              void* d_out, int out_size, void* d_ws, size_t ws_size,
                              hipStream_t stream)
{
    const float* src   = (const float*)d_in[0];
    const float* anc   = (const float*)d_in[1];
    const float* W_dim = (const float*)d_in[2];
    const float* b_dim = (const float*)d_in[3];
    const float* W_fus = (const float*)d_in[4];
    const float* b_fus = (const float*)d_in[5];
    const float* W_e1  = (const float*)d_in[6];
    const float* b_e1  = (const float*)d_in[7];
    const float* W_e2  = (const float*)d_in[8];
    const float* b_e2  = (const float*)d_in[9];
    const float* g1    = (const float*)d_in[10];
    const float* bt1   = (const float*)d_in[11];
    const float* g2    = (const float*)d_in[12];
    const float* bt2   = (const float*)d_in[13];
    const float* W_d   = (const float*)d_in[14];
    const float* b_d   = (const float*)d_in[15];
    const float* g_d   = (const float*)d_in[16];
    const float* bt_d  = (const float*)d_in[17];
    float* out = (float*)d_out;          // doubles as `comb`

    float* ws = (float*)d_ws;
    // Layout (floats), total 52,899,840 fl = 211.6 MB:
    //  [0)            seed score (dist) / h fp32 chunk (network)  16,777,216
    //  [16,777,216)   bufA: neigh -> enc2-out(t)                   8,388,608
    //  [25,165,824)   dist: src2+anc2 f16  |  network: weight f16 overlay
    //  [44,040,192)   W_comb2 | norm_a | sums | zeros | b_comb | bk/bi
    //  [44,478,464)   thrbuf 16384 | cnt 16384 | cand_k 4.19M | cand_i 4.19M
    float* score  = ws;
    float* bufA   = ws + 16777216;
    f16*   src2   = (f16*)(ws + 25165824);     // 16384 x 1536 f16
    f16*   anc2   = (f16*)(ws + 37748736);     // 8192 x 1536 f16
    f16*   wbase  = (f16*)(ws + 25165824);     // weight overlay (after dist)
    f16*   Wt_fus1  = wbase;                   // [512, 1024]
    f16*   Wt_comb2 = wbase + 524288;          // [512, 1024]
    f16*   Wt_e1    = wbase + 1048576;         // [2048, 1024]
    f16*   Wt_e2    = wbase + 3145728;         // [512, 4096]
    f16*   Wt_d     = wbase + 5242880;         // [512, 1024]
    float* W_comb2  = ws + 44040192;
    float* norm_a   = ws + 44302336;
    float* sums1    = ws + 44310528;
    float* sums2    = sums1 + 1024;
    float* sums3    = sums2 + 1024;
    float* zeros512 = ws + 44313600;
    float* b_comb   = ws + 44314112;
    float* bk_state = ws + 44314624;
    int*   bi_state = (int*)(ws + 44396544);
    float* thrbuf   = ws + 44478464;
    int*   cnt      = (int*)(ws + 44494848);
    float* cand_k   = ws + 44511232;
    int*   cand_i   = (int*)(ws + 48705536);

    const float invN = 1.0f / (float)N_ROWS;
    float* hbuf = score;   // network-phase alias

    zero_kernel<<<dim3(14), 256, 0, stream>>>(sums1, 3584);       // sums1..3 + zeros512
    zero_kernel<<<dim3(64), 256, 0, stream>>>((float*)cnt, 16384); // cnt = 0
    init_state_kernel<<<dim3(320), 256, 0, stream>>>(bk_state, bi_state, N_ROWS * KNN);
    split_kernel<0><<<dim3(N_ROWS * DDIM / 1024), 256, 0, stream>>>(src, src2, N_ROWS);
    split_kernel<1><<<dim3(M_ANCH * DDIM / 1024), 256, 0, stream>>>(anc, anc2, M_ANCH);
    anchor_norm_kernel<<<dim3(M_ANCH / 4), 256, 0, stream>>>(anc, norm_a);

    // dist: seed chunk (exact scan) then one big collect GEMM over the rest
    gemm_f16_nt<<<dim3(SEED / 128, N_ROWS / 128), 256, 0, stream>>>(
        src2, anc2, score, KSPLIT, SEED);
    topk_scan_kernel<<<dim3(N_ROWS / 4), 256, 0, stream>>>(
        score, norm_a, bk_state, bi_state, thrbuf, 0);
    gemm_collect<<<dim3((M_ANCH - SEED) / 128, N_ROWS / 128), 256, 0, stream>>>(
        src2, anc2 + (size_t)SEED * KSPLIT, norm_a + SEED, thrbuf,
        cnt, cand_k, cand_i, KSPLIT, SEED);
    cand_merge_kernel<<<dim3(64), 256, 0, stream>>>(cnt, cand_k, cand_i,
                                                    bk_state, bi_state);
    gather_mean_kernel<<<dim3(N_ROWS / 4), 256, 0, stream>>>(anc, bi_state, bufA);

    // Weight prep (overlays dead src2/anc2 region)
    wsplit_kernel<<<dim3(DDIM / 64, DDIM / 64), 256, 0, stream>>>(W_fus, Wt_fus1, DDIM, DDIM);
    wsplit_kernel<<<dim3(FDIM / 64, DDIM / 64), 256, 0, stream>>>(W_e1, Wt_e1, DDIM, FDIM);
    wsplit_kernel<<<dim3(DDIM / 64, FDIM / 64), 256, 0, stream>>>(W_e2, Wt_e2, FDIM, DDIM);
    wsplit_kernel<<<dim3(DDIM / 64, DDIM / 64), 256, 0, stream>>>(W_d, Wt_d, DDIM, DDIM);
    gemm_kernel<0><<<dim3(4, 4), 256, 0, stream>>>(
        W_dim, DDIM, nullptr, 0, W_fus + DDIM * DDIM, zeros512, W_comb2, DDIM);
    bcomb_kernel<<<dim3(2), 256, 0, stream>>>(b_dim, W_fus + DDIM * DDIM, b_fus, b_comb);
    wsplit_kernel<<<dim3(DDIM / 64, DDIM / 64), 256, 0, stream>>>(W_comb2, Wt_comb2, DDIM, DDIM);

    // comb = src @ Wf1 + b_comb + neigh @ W_comb2   -> out, then BN1
    gemm_split_nt<0, 0><<<dim3(DDIM / 128, N_ROWS / 128), 256, 0, stream>>>(
        src, Wt_fus1, b_comb, nullptr, out, DDIM, DDIM);
    gemm_split_nt<1, 0><<<dim3(DDIM / 128, N_ROWS / 128), 256, 0, stream>>>(
        bufA, Wt_comb2, nullptr, out, out, DDIM, DDIM);
    bn_stats_kernel<<<dim3(DDIM / 64, 16), 256, 0, stream>>>(out, sums1);
    bn_apply_kernel<0><<<dim3(8192), 256, 0, stream>>>(out, out, sums1, g1, bt1, invN);

    // encoder, chunked: h = tanh(comb@We1+b1); t = h@We2 + b2 + comb
    for (int r0 = 0; r0 < N_ROWS; r0 += CHUNK) {
        gemm_split_nt<0, 1><<<dim3(FDIM / 128, CHUNK / 128), 256, 0, stream>>>(
            out + (size_t)r0 * DDIM, Wt_e1, b_e1, nullptr, hbuf, DDIM, FDIM);
        gemm_split_nt<1, 0><<<dim3(DDIM / 128, CHUNK / 128), 256, 0, stream>>>(
            hbuf, Wt_e2, b_e2, out + (size_t)r0 * DDIM, bufA + (size_t)r0 * DDIM,
            FDIM, DDIM);
    }
    bn_stats_kernel<<<dim3(DDIM / 64, 16), 256, 0, stream>>>(bufA, sums2);
    bn_apply_kernel<0><<<dim3(8192), 256, 0, stream>>>(bufA, bufA, sums2, g2, bt2, invN);

    // decoder -> out, BN3 + tanh
    gemm_split_nt<0, 0><<<dim3(DDIM / 128, N_ROWS / 128), 256, 0, stream>>>(
        bufA, Wt_d, b_d, nullptr, out, DDIM, DDIM);
    bn_stats_kernel<<<dim3(DDIM / 64, 16), 256, 0, stream>>>(out, sums3);
    bn_apply_kernel<1><<<dim3(8192), 256, 0, stream>>>(out, out, sums3, g_d, bt_d, invN);
}

// Round 7
// 1778.209 us; speedup vs baseline: 2.6197x; 1.0695x over previous
//
#include <hip/hip_runtime.h>
#include <math.h>

#define N_ROWS 16384
#define M_ANCH 8192
#define DDIM   512
#define FDIM   2048
#define KNN    5
#define BN_EPS 1e-5f
#define CHUNK  8192    // network-phase row chunk (h fp32 chunk = 64 MB, in score region)
#define SEED   1024    // dist seed chunk (exact scan); rest via candidate collection
#define KSPLIT 1536    // 3 x 512 virtual-K for dist hi/lo split product
#define CAND_MAX 256   // per-row candidate buffer (E~35, P(overflow)~3e-10 at SEED=1024)

typedef _Float16 f16;
typedef _Float16 f16x8 __attribute__((ext_vector_type(8)));
typedef _Float16 f16x4 __attribute__((ext_vector_type(4)));
typedef float f32x4 __attribute__((ext_vector_type(4)));

__device__ __forceinline__ void async_copy16(const void* g, void* l) {
    __builtin_amdgcn_global_load_lds(
        (const __attribute__((address_space(1))) void*)g,
        (__attribute__((address_space(3))) void*)l, 16, 0, 0);
}

__device__ __forceinline__ bool kless(float k1, int i1, float k2, int i2) {
    return (k1 < k2) || (k1 == k2 && i1 < i2);
}

__device__ __forceinline__ void insert5(float (&bk)[KNN], int (&bi)[KNN], float key, int id) {
    if (!kless(key, id, bk[4], bi[4])) return;
    bool c3 = kless(key, id, bk[3], bi[3]);
    bool c2 = kless(key, id, bk[2], bi[2]);
    bool c1 = kless(key, id, bk[1], bi[1]);
    bool c0 = kless(key, id, bk[0], bi[0]);
    bk[4] = c3 ? bk[3] : key;                  bi[4] = c3 ? bi[3] : id;
    bk[3] = c3 ? (c2 ? bk[2] : key) : bk[3];   bi[3] = c3 ? (c2 ? bi[2] : id) : bi[3];
    bk[2] = c2 ? (c1 ? bk[1] : key) : bk[2];   bi[2] = c2 ? (c1 ? bi[1] : id) : bi[2];
    bk[1] = c1 ? (c0 ? bk[0] : key) : bk[1];   bi[1] = c1 ? (c0 ? bi[0] : id) : bi[1];
    bk[0] = c0 ? key : bk[0];                  bi[0] = c0 ? id : bi[0];
}

__global__ void zero_kernel(float* p, int n) {
    int i = blockIdx.x * blockDim.x + threadIdx.x;
    if (i < n) p[i] = 0.f;
}

// fp32 -> f16 hi/lo split into virtual-K layout (dist phase).
// MODE 0 (src): segs [hi | lo | hi];  MODE 1 (anchor): segs [hi | hi | lo]
template<int MODE>
__global__ __launch_bounds__(256) void split_kernel(const float* __restrict__ X,
                                                    f16* __restrict__ Y, int nrows) {
    int i4 = blockIdx.x * 256 + threadIdx.x;
    int row = i4 >> 7;
    int kc = (i4 & 127) * 4;
    if (row >= nrows) return;
    float4 v = ((const float4*)X)[i4];
    f16x4 h, lo;
    h.x = (f16)v.x; h.y = (f16)v.y; h.z = (f16)v.z; h.w = (f16)v.w;
    lo.x = (f16)(v.x - (float)h.x); lo.y = (f16)(v.y - (float)h.y);
    lo.z = (f16)(v.z - (float)h.z); lo.w = (f16)(v.w - (float)h.w);
    f16* base = Y + (size_t)row * KSPLIT + kc;
    if (MODE == 0) {
        *(f16x4*)(base) = h; *(f16x4*)(base + 512) = lo; *(f16x4*)(base + 1024) = h;
    } else {
        *(f16x4*)(base) = h; *(f16x4*)(base + 512) = h;  *(f16x4*)(base + 1024) = lo;
    }
}

__global__ __launch_bounds__(256) void anchor_norm_kernel(const float* __restrict__ a,
                                                          float* __restrict__ norm_a) {
    int wave = threadIdx.x >> 6, lane = threadIdx.x & 63;
    int row = blockIdx.x * 4 + wave;
    const float4* ar = (const float4*)(a + (size_t)row * DDIM);
    float4 v1 = ar[lane * 2];
    float4 v2 = ar[lane * 2 + 1];
    float s = v1.x*v1.x + v1.y*v1.y + v1.z*v1.z + v1.w*v1.w
            + v2.x*v2.x + v2.y*v2.y + v2.z*v2.z + v2.w*v2.w;
    for (int off = 32; off; off >>= 1) s += __shfl_xor(s, off, 64);
    if (lane == 0) norm_a[row] = s;
}

// Seed dist GEMM: writes key = norm[n] - 2*(A.B) directly.
// LDS swizzle: row r's k-quad q lives at quad slot (q + (r>>1))&3.
template<int K>
__global__ __launch_bounds__(256) void gemm_f16_key(
    const f16* __restrict__ A, const f16* __restrict__ B,
    const float* __restrict__ norm, float* __restrict__ C, int Ncols)
{
    __shared__ f16 As[128 * 32];
    __shared__ f16 Bs[128 * 32];
    const int t = threadIdx.x;
    const int w = t >> 6, l = t & 63;
    const int m0 = blockIdx.y * 128, n0 = blockIdx.x * 128;
    const int wm = (w & 1) * 64, wn = (w >> 1) * 64;

    f32x4 acc[4][4];
    #pragma unroll
    for (int i = 0; i < 4; ++i)
        #pragma unroll
        for (int j = 0; j < 4; ++j) acc[i][j] = (f32x4){0.f, 0.f, 0.f, 0.f};

    const int srow = l >> 2;
    const int gq = ((l & 3) - (srow >> 1)) & 3;   // swizzled global k-quad
    const int skoff = gq * 8;
    const int sqf = (((l >> 4) + (((l & 15) >> 1) & 3)) & 3) * 8;  // frag read slot

    for (int k0 = 0; k0 < K; k0 += 32) {
        __syncthreads();
        #pragma unroll
        for (int s = 0; s < 2; ++s) {
            int grp = w * 2 + s;
            int row = grp * 16 + srow;
            async_copy16(A + (size_t)(m0 + row) * K + k0 + skoff, As + grp * 512 + l * 8);
            async_copy16(B + (size_t)(n0 + row) * K + k0 + skoff, Bs + grp * 512 + l * 8);
        }
        __syncthreads();
        f16x8 af[4], bf[4];
        #pragma unroll
        for (int i = 0; i < 4; ++i)
            af[i] = *(const f16x8*)(As + (wm + i * 16 + (l & 15)) * 32 + sqf);
        #pragma unroll
        for (int j = 0; j < 4; ++j)
            bf[j] = *(const f16x8*)(Bs + (wn + j * 16 + (l & 15)) * 32 + sqf);
        #pragma unroll
        for (int i = 0; i < 4; ++i)
            #pragma unroll
            for (int j = 0; j < 4; ++j)
                acc[i][j] = __builtin_amdgcn_mfma_f32_16x16x32_f16(af[i], bf[j], acc[i][j], 0, 0, 0);
    }
    float nj[4];
    #pragma unroll
    for (int j = 0; j < 4; ++j) nj[j] = norm[n0 + wn + j * 16 + (l & 15)];
    #pragma unroll
    for (int i = 0; i < 4; ++i)
        #pragma unroll
        for (int j = 0; j < 4; ++j)
            #pragma unroll
            for (int r = 0; r < 4; ++r) {
                int m = m0 + wm + i * 16 + (l >> 4) * 4 + r;
                int n = n0 + wn + j * 16 + (l & 15);
                C[(size_t)m * Ncols + n] = nj[j] - 2.f * acc[i][j][r];
            }
}

// Collect GEMM for anchors [SEED..M): appends (key,id) with key < thr[row] to
// per-row candidate lists (exact: seed ids are smaller, ties lose by id).
template<int K>
__global__ __launch_bounds__(256) void gemm_collect(
    const f16* __restrict__ A, const f16* __restrict__ B,
    const float* __restrict__ norm, const float* __restrict__ thr,
    int* __restrict__ cnt, float* __restrict__ cand_k, int* __restrict__ cand_i,
    int idofs)
{
    __shared__ f16 As[128 * 32];
    __shared__ f16 Bs[128 * 32];
    const int t = threadIdx.x;
    const int w = t >> 6, l = t & 63;
    const int m0 = blockIdx.y * 128, n0 = blockIdx.x * 128;
    const int wm = (w & 1) * 64, wn = (w >> 1) * 64;

    f32x4 acc[4][4];
    #pragma unroll
    for (int i = 0; i < 4; ++i)
        #pragma unroll
        for (int j = 0; j < 4; ++j) acc[i][j] = (f32x4){0.f, 0.f, 0.f, 0.f};

    const int srow = l >> 2;
    const int gq = ((l & 3) - (srow >> 1)) & 3;
    const int skoff = gq * 8;
    const int sqf = (((l >> 4) + (((l & 15) >> 1) & 3)) & 3) * 8;

    for (int k0 = 0; k0 < K; k0 += 32) {
        __syncthreads();
        #pragma unroll
        for (int s = 0; s < 2; ++s) {
            int grp = w * 2 + s;
            int row = grp * 16 + srow;
            async_copy16(A + (size_t)(m0 + row) * K + k0 + skoff, As + grp * 512 + l * 8);
            async_copy16(B + (size_t)(n0 + row) * K + k0 + skoff, Bs + grp * 512 + l * 8);
        }
        __syncthreads();
        f16x8 af[4], bf[4];
        #pragma unroll
        for (int i = 0; i < 4; ++i)
            af[i] = *(const f16x8*)(As + (wm + i * 16 + (l & 15)) * 32 + sqf);
        #pragma unroll
        for (int j = 0; j < 4; ++j)
            bf[j] = *(const f16x8*)(Bs + (wn + j * 16 + (l & 15)) * 32 + sqf);
        #pragma unroll
        for (int i = 0; i < 4; ++i)
            #pragma unroll
            for (int j = 0; j < 4; ++j)
                acc[i][j] = __builtin_amdgcn_mfma_f32_16x16x32_f16(af[i], bf[j], acc[i][j], 0, 0, 0);
    }
    float thr4[4][4];
    #pragma unroll
    for (int i = 0; i < 4; ++i) {
        float4 tv = *(const float4*)&thr[m0 + wm + i * 16 + (l >> 4) * 4];
        thr4[i][0] = tv.x; thr4[i][1] = tv.y; thr4[i][2] = tv.z; thr4[i][3] = tv.w;
    }
    float nj[4];
    #pragma unroll
    for (int j = 0; j < 4; ++j) nj[j] = norm[n0 + wn + j * 16 + (l & 15)];
    #pragma unroll
    for (int i = 0; i < 4; ++i)
        #pragma unroll
        for (int j = 0; j < 4; ++j)
            #pragma unroll
            for (int r = 0; r < 4; ++r) {
                float key = nj[j] - 2.f * acc[i][j][r];
                if (key < thr4[i][r]) {
                    int row = m0 + wm + i * 16 + (l >> 4) * 4 + r;
                    int pos = atomicAdd(&cnt[row], 1);
                    if (pos < CAND_MAX) {
                        cand_k[(size_t)row * CAND_MAX + pos] = key;
                        cand_i[(size_t)row * CAND_MAX + pos] =
                            idofs + n0 + wn + j * 16 + (l & 15);
                    }
                }
            }
}

// exact top-5 over seed keys (pre-computed); writes thrbuf = 5th-best.
// One wave per row; 16 keys/lane loaded up-front (4 independent float4s).
__global__ __launch_bounds__(256) void topk_scan_kernel(
    const float* __restrict__ g, float* __restrict__ bk_state,
    int* __restrict__ bi_state, float* __restrict__ thrbuf)
{
    int row = blockIdx.x * 4 + (threadIdx.x >> 6);
    int lane = threadIdx.x & 63;
    const float* grow = g + (size_t)row * SEED;
    float4 v0 = *(const float4*)(grow + lane * 4);
    float4 v1 = *(const float4*)(grow + 256 + lane * 4);
    float4 v2 = *(const float4*)(grow + 512 + lane * 4);
    float4 v3 = *(const float4*)(grow + 768 + lane * 4);
    float bk[KNN]; int bi[KNN];
    #pragma unroll
    for (int q = 0; q < KNN; ++q) { bk[q] = 3.0e38f; bi[q] = 0x7fffffff; }
    int c = lane * 4;
    insert5(bk, bi, v0.x, c);       insert5(bk, bi, v0.y, c + 1);
    insert5(bk, bi, v0.z, c + 2);   insert5(bk, bi, v0.w, c + 3);
    insert5(bk, bi, v1.x, c + 256); insert5(bk, bi, v1.y, c + 257);
    insert5(bk, bi, v1.z, c + 258); insert5(bk, bi, v1.w, c + 259);
    insert5(bk, bi, v2.x, c + 512); insert5(bk, bi, v2.y, c + 513);
    insert5(bk, bi, v2.z, c + 514); insert5(bk, bi, v2.w, c + 515);
    insert5(bk, bi, v3.x, c + 768); insert5(bk, bi, v3.y, c + 769);
    insert5(bk, bi, v3.z, c + 770); insert5(bk, bi, v3.w, c + 771);
    for (int off = 32; off >= 1; off >>= 1) {
        float ok[KNN]; int oi[KNN];
        #pragma unroll
        for (int q = 0; q < KNN; ++q) {
            ok[q] = __shfl_xor(bk[q], off, 64);
            oi[q] = __shfl_xor(bi[q], off, 64);
        }
        #pragma unroll
        for (int q = 0; q < KNN; ++q) insert5(bk, bi, ok[q], oi[q]);
    }
    if (lane == 0) {
        #pragma unroll
        for (int q = 0; q < KNN; ++q) {
            bk_state[row * KNN + q] = bk[q];
            bi_state[row * KNN + q] = bi[q];
        }
        thrbuf[row] = bk[4];
    }
}

// merge collected candidates into seeded top-5; writes final indices.
__global__ __launch_bounds__(256) void cand_merge_kernel(
    const int* __restrict__ cnt, const float* __restrict__ cand_k,
    const int* __restrict__ cand_i, float* __restrict__ bk_state,
    int* __restrict__ bi_state)
{
    int row = blockIdx.x * 256 + threadIdx.x;
    if (row >= N_ROWS) return;
    float bk[KNN]; int bi[KNN];
    #pragma unroll
    for (int q = 0; q < KNN; ++q) {
        bk[q] = bk_state[row * KNN + q];
        bi[q] = bi_state[row * KNN + q];
    }
    int c = cnt[row]; if (c > CAND_MAX) c = CAND_MAX;
    const float* ck = cand_k + (size_t)row * CAND_MAX;
    const int*   ci = cand_i + (size_t)row * CAND_MAX;
    for (int p = 0; p < c; ++p) insert5(bk, bi, ck[p], ci[p]);
    #pragma unroll
    for (int q = 0; q < KNN; ++q) bi_state[row * KNN + q] = bi[q];
}

__global__ __launch_bounds__(256) void gather_mean_kernel(
    const float* __restrict__ anchor, const int* __restrict__ bi_state,
    float* __restrict__ neigh)
{
    int row = blockIdx.x * 4 + (threadIdx.x >> 6);
    int lane = threadIdx.x & 63;
    const int* bi = bi_state + row * KNN;
    int i0 = bi[0], i1 = bi[1], i2 = bi[2], i3 = bi[3], i4 = bi[4];
    const float4* a0 = (const float4*)(anchor + (size_t)i0 * DDIM);
    const float4* a1 = (const float4*)(anchor + (size_t)i1 * DDIM);
    const float4* a2 = (const float4*)(anchor + (size_t)i2 * DDIM);
    const float4* a3 = (const float4*)(anchor + (size_t)i3 * DDIM);
    const float4* a4 = (const float4*)(anchor + (size_t)i4 * DDIM);
    float4* np = (float4*)(neigh + (size_t)row * DDIM);
    #pragma unroll
    for (int p = 0; p < 2; ++p) {
        int c4 = lane + 64 * p;
        float4 v0 = a0[c4], v1 = a1[c4], v2 = a2[c4], v3 = a3[c4], v4 = a4[c4];
        float4 o;
        o.x = (v0.x + v1.x + v2.x + v3.x + v4.x) * 0.2f;
        o.y = (v0.y + v1.y + v2.y + v3.y + v4.y) * 0.2f;
        o.z = (v0.z + v1.z + v2.z + v3.z + v4.z) * 0.2f;
        o.w = (v0.w + v1.w + v2.w + v3.w + v4.w) * 0.2f;
        np[c4] = o;
    }
}

// Network GEMM: C = act(A @ BwT + bias [+ C0]).  A fp32 split in-kernel to f16
// hi/lo LDS tiles; Bw pre-split f16 [N, hi(K)|lo(K)].  3-term -> fp32-grade.
// Same LDS swizzle as the dist GEMMs.
template<int ADDC0, int TANH, int K>
__global__ __launch_bounds__(256) void gemm_split_nt(
    const float* __restrict__ A, const f16* __restrict__ Bw,
    const float* __restrict__ bias, const float* __restrict__ C0,
    float* __restrict__ C, int Ncols)
{
    __shared__ f16 Ah[128 * 32];
    __shared__ f16 Al[128 * 32];
    __shared__ f16 Bh[128 * 32];
    __shared__ f16 Bl[128 * 32];
    const int t = threadIdx.x;
    const int w = t >> 6, l = t & 63;
    const int m0 = blockIdx.y * 128, n0 = blockIdx.x * 128;
    const int wm = (w & 1) * 64, wn = (w >> 1) * 64;
    const int K2 = 2 * K;

    f32x4 acc[4][4];
    #pragma unroll
    for (int i = 0; i < 4; ++i)
        #pragma unroll
        for (int j = 0; j < 4; ++j) acc[i][j] = (f32x4){0.f, 0.f, 0.f, 0.f};

    const int ar = t >> 1;           // A staging: row 0..127
    const int ac = (t & 1) * 16;     // global k offset (f16): 0 or 16
    const int arq = (ar >> 1) & 3;
    const int s0 = (((t & 1) * 2 + 0 + arq) & 3) * 8;   // swizzled LDS quads
    const int s1 = (((t & 1) * 2 + 1 + arq) & 3) * 8;
    const int srow = l >> 2;         // B staging
    const int gq = ((l & 3) - (srow >> 1)) & 3;
    const int skoff = gq * 8;
    const int sqf = (((l >> 4) + (((l & 15) >> 1) & 3)) & 3) * 8;

    for (int k0 = 0; k0 < K; k0 += 32) {
        __syncthreads();
        #pragma unroll
        for (int s = 0; s < 2; ++s) {
            int grp = w * 2 + s;
            int row = grp * 16 + srow;
            const f16* bp = Bw + (size_t)(n0 + row) * K2 + k0 + skoff;
            async_copy16(bp, Bh + grp * 512 + l * 8);
            async_copy16(bp + K, Bl + grp * 512 + l * 8);
        }
        {
            const float* ap = A + (size_t)(m0 + ar) * K + k0 + ac;
            float xs[16];
            *(float4*)&xs[0]  = *(const float4*)ap;
            *(float4*)&xs[4]  = *(const float4*)(ap + 4);
            *(float4*)&xs[8]  = *(const float4*)(ap + 8);
            *(float4*)&xs[12] = *(const float4*)(ap + 12);
            f16x8 h0, h1, lo0, lo1;
            #pragma unroll
            for (int e = 0; e < 8; ++e) {
                f16 hh = (f16)xs[e];
                h0[e] = hh; lo0[e] = (f16)(xs[e] - (float)hh);
                f16 hh2 = (f16)xs[8 + e];
                h1[e] = hh2; lo1[e] = (f16)(xs[8 + e] - (float)hh2);
            }
            *(f16x8*)&Ah[ar * 32 + s0] = h0;  *(f16x8*)&Ah[ar * 32 + s1] = h1;
            *(f16x8*)&Al[ar * 32 + s0] = lo0; *(f16x8*)&Al[ar * 32 + s1] = lo1;
        }
        __syncthreads();
        f16x8 afh[4], afl[4], bfh[4], bfl[4];
        #pragma unroll
        for (int i = 0; i < 4; ++i) {
            int base = (wm + i * 16 + (l & 15)) * 32 + sqf;
            afh[i] = *(const f16x8*)(Ah + base);
            afl[i] = *(const f16x8*)(Al + base);
        }
        #pragma unroll
        for (int j = 0; j < 4; ++j) {
            int base = (wn + j * 16 + (l & 15)) * 32 + sqf;
            bfh[j] = *(const f16x8*)(Bh + base);
            bfl[j] = *(const f16x8*)(Bl + base);
        }
        #pragma unroll
        for (int i = 0; i < 4; ++i)
            #pragma unroll
            for (int j = 0; j < 4; ++j) {
                acc[i][j] = __builtin_amdgcn_mfma_f32_16x16x32_f16(afh[i], bfh[j], acc[i][j], 0, 0, 0);
                acc[i][j] = __builtin_amdgcn_mfma_f32_16x16x32_f16(afl[i], bfh[j], acc[i][j], 0, 0, 0);
                acc[i][j] = __builtin_amdgcn_mfma_f32_16x16x32_f16(afh[i], bfl[j], acc[i][j], 0, 0, 0);
            }
    }
    float bv[4];
    #pragma unroll
    for (int j = 0; j < 4; ++j)
        bv[j] = bias ? bias[n0 + wn + j * 16 + (l & 15)] : 0.f;
    #pragma unroll
    for (int i = 0; i < 4; ++i)
        #pragma unroll
        for (int j = 0; j < 4; ++j)
            #pragma unroll
            for (int r = 0; r < 4; ++r) {
                int m = m0 + wm + i * 16 + (l >> 4) * 4 + r;
                int n = n0 + wn + j * 16 + (l & 15);
                float v = acc[i][j][r] + bv[j];
                if (ADDC0) v += C0[(size_t)m * Ncols + n];
                if (TANH)  v = tanhf(v);
                C[(size_t)m * Ncols + n] = v;
            }
}

// Weight transpose + hi/lo split: W [K,N] fp32 -> Wt [N, hi(K)|lo(K)] f16.
__global__ __launch_bounds__(256) void wsplit_kernel(const float* __restrict__ W,
                                                     f16* __restrict__ Wt,
                                                     int K, int N)
{
    __shared__ float tile[64][65];
    const int t = threadIdx.x;
    const int kb = blockIdx.y * 64, nb = blockIdx.x * 64;
    #pragma unroll
    for (int i = 0; i < 4; ++i) {
        int r = (t >> 4) + i * 16;
        int c = (t & 15) * 4;
        *(float4*)&tile[r][c] = *(const float4*)&W[(size_t)(kb + r) * N + nb + c];
    }
    __syncthreads();
    const int r2 = t >> 2;
    const int kc = (t & 3) * 16;
    f16x8 h0, h1, lo0, lo1;
    #pragma unroll
    for (int e = 0; e < 8; ++e) {
        float x = tile[kc + e][r2];
        f16 hh = (f16)x; h0[e] = hh; lo0[e] = (f16)(x - (float)hh);
        float y = tile[kc + 8 + e][r2];
        f16 hh2 = (f16)y; h1[e] = hh2; lo1[e] = (f16)(y - (float)hh2);
    }
    f16* base = Wt + (size_t)(nb + r2) * 2 * K + kb + kc;
    *(f16x8*)base = h0; *(f16x8*)(base + 8) = h1;
    *(f16x8*)(base + K) = lo0; *(f16x8*)(base + K + 8) = lo1;
}

// b_comb[n] = sum_k b_dim[k] * W_fus[512+k][n] + b_fus[n]
__global__ __launch_bounds__(256) void bcomb_kernel(const float* __restrict__ b_dim,
                                                    const float* __restrict__ W_fus2,
                                                    const float* __restrict__ b_fus,
                                                    float* __restrict__ b_comb)
{
    int n = blockIdx.x * 256 + threadIdx.x;
    if (n >= DDIM) return;
    float s = b_fus[n];
    for (int k = 0; k < DDIM; ++k) s += b_dim[k] * W_fus2[(size_t)k * DDIM + n];
    b_comb[n] = s;
}

// fp32 GEMM (used only for the tiny W_comb2 = W_dim @ W_fus2 fold).
template<int ACT>
__global__ __launch_bounds__(256) void gemm_kernel(
    const float* __restrict__ A, int K1,
    const float* __restrict__ A2, int K2,
    const float* __restrict__ B, const float* __restrict__ bias,
    float* __restrict__ C, int Ncols)
{
    __shared__ float As[16][132];
    __shared__ float Bs[16][128];
    const int t = threadIdx.x;
    const int n0 = blockIdx.x * 128;
    const int m0 = blockIdx.y * 128;
    const int ty = t >> 4, tx = t & 15;
    const int K = K1 + K2;

    float acc[8][8];
    #pragma unroll
    for (int i = 0; i < 8; ++i)
        #pragma unroll
        for (int j = 0; j < 8; ++j) acc[i][j] = 0.f;

    const int ar = t >> 1;
    const int akc = (t & 1) * 8;
    const int bkr = t >> 4;
    const int bc = (t & 15) * 8;

    for (int k0 = 0; k0 < K; k0 += 16) {
        int kk = k0 + akc;
        float4 v0, v1;
        if (kk < K1) {
            const float* p = A + (size_t)(m0 + ar) * K1 + kk;
            v0 = *(const float4*)p; v1 = *(const float4*)(p + 4);
        } else {
            const float* p = A2 + (size_t)(m0 + ar) * K2 + (kk - K1);
            v0 = *(const float4*)p; v1 = *(const float4*)(p + 4);
        }
        const float* bp = B + (size_t)(k0 + bkr) * Ncols + n0 + bc;
        float4 w0 = *(const float4*)bp, w1 = *(const float4*)(bp + 4);
        __syncthreads();
        As[akc+0][ar] = v0.x; As[akc+1][ar] = v0.y; As[akc+2][ar] = v0.z; As[akc+3][ar] = v0.w;
        As[akc+4][ar] = v1.x; As[akc+5][ar] = v1.y; As[akc+6][ar] = v1.z; As[akc+7][ar] = v1.w;
        *(float4*)&Bs[bkr][bc] = w0; *(float4*)&Bs[bkr][bc + 4] = w1;
        __syncthreads();
        #pragma unroll
        for (int k = 0; k < 16; ++k) {
            float a[8], b[8];
            *(float4*)&a[0] = *(const float4*)&As[k][ty * 8];
            *(float4*)&a[4] = *(const float4*)&As[k][ty * 8 + 4];
            *(float4*)&b[0] = *(const float4*)&Bs[k][tx * 4];
            *(float4*)&b[4] = *(const float4*)&Bs[k][64 + tx * 4];
            #pragma unroll
            for (int i = 0; i < 8; ++i)
                #pragma unroll
                for (int j = 0; j < 8; ++j) acc[i][j] += a[i] * b[j];
        }
    }
    float4 bv0 = *(const float4*)(bias + n0 + tx * 4);
    float4 bv1 = *(const float4*)(bias + n0 + 64 + tx * 4);
    #pragma unroll
    for (int i = 0; i < 8; ++i) {
        int row = m0 + ty * 8 + i;
        float4 o0, o1;
        o0.x = acc[i][0] + bv0.x; o0.y = acc[i][1] + bv0.y;
        o0.z = acc[i][2] + bv0.z; o0.w = acc[i][3] + bv0.w;
        o1.x = acc[i][4] + bv1.x; o1.y = acc[i][5] + bv1.y;
        o1.z = acc[i][6] + bv1.z; o1.w = acc[i][7] + bv1.w;
        if (ACT == 1) {
            o0.x = tanhf(o0.x); o0.y = tanhf(o0.y); o0.z = tanhf(o0.z); o0.w = tanhf(o0.w);
            o1.x = tanhf(o1.x); o1.y = tanhf(o1.y); o1.z = tanhf(o1.z); o1.w = tanhf(o1.w);
        }
        *(float4*)(C + (size_t)row * Ncols + n0 + tx * 4) = o0;
        *(float4*)(C + (size_t)row * Ncols + n0 + 64 + tx * 4) = o1;
    }
}

__global__ __launch_bounds__(256) void bn_stats_kernel(const float* __restrict__ X,
                                                       float* __restrict__ sums)
{
    __shared__ float red[8][64];
    int lane = threadIdx.x & 63;
    int rl = threadIdx.x >> 6;
    int c = blockIdx.x * 64 + lane;
    int chunk = N_ROWS / gridDim.y;
    int rbeg = blockIdx.y * chunk;
    float s = 0.f, s2 = 0.f;
    for (int r = rbeg + rl; r < rbeg + chunk; r += 4) {
        float v = X[(size_t)r * DDIM + c];
        s += v; s2 += v * v;
    }
    red[rl][lane] = s; red[4 + rl][lane] = s2;
    __syncthreads();
    if (threadIdx.x < 64) {
        float ts = red[0][lane] + red[1][lane] + red[2][lane] + red[3][lane];
        float t2 = red[4][lane] + red[5][lane] + red[6][lane] + red[7][lane];
        atomicAdd(&sums[c], ts);
        atomicAdd(&sums[DDIM + c], t2);
    }
}

template<int TANH>
__global__ __launch_bounds__(256) void bn_apply_kernel(
    const float* __restrict__ X, float* __restrict__ Y,
    const float* __restrict__ sums, const float* __restrict__ g,
    const float* __restrict__ b, float invN)
{
    size_t i = (size_t)blockIdx.x * 256 + threadIdx.x;
    int cg = (int)(i % (DDIM / 4));
    int c = cg * 4;
    float4 x = ((const float4*)X)[i];
    float4 sm = *(const float4*)(sums + c);
    float4 sq = *(const float4*)(sums + DDIM + c);
    float4 gv = *(const float4*)(g + c);
    float4 bv = *(const float4*)(b + c);
    float m, var, rs;
    m = sm.x * invN; var = sq.x * invN - m * m; rs = rsqrtf(var + BN_EPS);
    x.x = (x.x - m) * rs * gv.x + bv.x;
    m = sm.y * invN; var = sq.y * invN - m * m; rs = rsqrtf(var + BN_EPS);
    x.y = (x.y - m) * rs * gv.y + bv.y;
    m = sm.z * invN; var = sq.z * invN - m * m; rs = rsqrtf(var + BN_EPS);
    x.z = (x.z - m) * rs * gv.z + bv.z;
    m = sm.w * invN; var = sq.w * invN - m * m; rs = rsqrtf(var + BN_EPS);
    x.w = (x.w - m) * rs * gv.w + bv.w;
    if (TANH) { x.x = tanhf(x.x); x.y = tanhf(x.y); x.z = tanhf(x.z); x.w = tanhf(x.w); }
    ((float4*)Y)[i] = x;
}

extern "C" void kernel_launch(void* const* d_in, const int* in_sizes, int n_in,
                              void* d_out, int out_size, void* d_ws, size_t ws_size,
                              hipStream_t stream)
{
    const float* src   = (const float*)d_in[0];
    const float* anc   = (const float*)d_in[1];
    const float* W_dim = (const float*)d_in[2];
    const float* b_dim = (const float*)d_in[3];
    const float* W_fus = (const float*)d_in[4];
    const float* b_fus = (const float*)d_in[5];
    const float* W_e1  = (const float*)d_in[6];
    const float* b_e1  = (const float*)d_in[7];
    const float* W_e2  = (const float*)d_in[8];
    const float* b_e2  = (const float*)d_in[9];
    const float* g1    = (const float*)d_in[10];
    const float* bt1   = (const float*)d_in[11];
    const float* g2    = (const float*)d_in[12];
    const float* bt2   = (const float*)d_in[13];
    const float* W_d   = (const float*)d_in[14];
    const float* b_d   = (const float*)d_in[15];
    const float* g_d   = (const float*)d_in[16];
    const float* bt_d  = (const float*)d_in[17];
    float* out = (float*)d_out;          // doubles as `comb`

    float* ws = (float*)d_ws;
    // Layout (floats), total 52,899,840 fl = 211.6 MB (see R6 comment).
    float* score  = ws;
    float* bufA   = ws + 16777216;
    f16*   src2   = (f16*)(ws + 25165824);     // 16384 x 1536 f16
    f16*   anc2   = (f16*)(ws + 37748736);     // 8192 x 1536 f16
    f16*   wbase  = (f16*)(ws + 25165824);     // weight overlay (after dist)
    f16*   Wt_fus1  = wbase;                   // [512, 1024]
    f16*   Wt_comb2 = wbase + 524288;          // [512, 1024]
    f16*   Wt_e1    = wbase + 1048576;         // [2048, 1024]
    f16*   Wt_e2    = wbase + 3145728;         // [512, 4096]
    f16*   Wt_d     = wbase + 5242880;         // [512, 1024]
    float* W_comb2  = ws + 44040192;
    float* norm_a   = ws + 44302336;
    float* sums1    = ws + 44310528;
    float* sums2    = sums1 + 1024;
    float* sums3    = sums2 + 1024;
    float* zeros512 = ws + 44313600;
    float* b_comb   = ws + 44314112;
    float* bk_state = ws + 44314624;
    int*   bi_state = (int*)(ws + 44396544);
    float* thrbuf   = ws + 44478464;
    int*   cnt      = (int*)(ws + 44494848);
    float* cand_k   = ws + 44511232;
    int*   cand_i   = (int*)(ws + 48705536);

    const float invN = 1.0f / (float)N_ROWS;
    float* hbuf = score;   // network-phase alias

    zero_kernel<<<dim3(14), 256, 0, stream>>>(sums1, 3584);        // sums1..3 + zeros512
    zero_kernel<<<dim3(64), 256, 0, stream>>>((float*)cnt, 16384); // cnt = 0
    split_kernel<0><<<dim3(N_ROWS * DDIM / 1024), 256, 0, stream>>>(src, src2, N_ROWS);
    split_kernel<1><<<dim3(M_ANCH * DDIM / 1024), 256, 0, stream>>>(anc, anc2, M_ANCH);
    anchor_norm_kernel<<<dim3(M_ANCH / 4), 256, 0, stream>>>(anc, norm_a);

    // dist: seed chunk (keys + exact scan) then one big collect GEMM
    gemm_f16_key<KSPLIT><<<dim3(SEED / 128, N_ROWS / 128), 256, 0, stream>>>(
        src2, anc2, norm_a, score, SEED);
    topk_scan_kernel<<<dim3(N_ROWS / 4), 256, 0, stream>>>(
        score, bk_state, bi_state, thrbuf);
    gemm_collect<KSPLIT><<<dim3((M_ANCH - SEED) / 128, N_ROWS / 128), 256, 0, stream>>>(
        src2, anc2 + (size_t)SEED * KSPLIT, norm_a + SEED, thrbuf,
        cnt, cand_k, cand_i, SEED);
    cand_merge_kernel<<<dim3(64), 256, 0, stream>>>(cnt, cand_k, cand_i,
                                                    bk_state, bi_state);
    gather_mean_kernel<<<dim3(N_ROWS / 4), 256, 0, stream>>>(anc, bi_state, bufA);

    // Weight prep (overlays dead src2/anc2 region)
    wsplit_kernel<<<dim3(DDIM / 64, DDIM / 64), 256, 0, stream>>>(W_fus, Wt_fus1, DDIM, DDIM);
    wsplit_kernel<<<dim3(FDIM / 64, DDIM / 64), 256, 0, stream>>>(W_e1, Wt_e1, DDIM, FDIM);
    wsplit_kernel<<<dim3(DDIM / 64, FDIM / 64), 256, 0, stream>>>(W_e2, Wt_e2, FDIM, DDIM);
    wsplit_kernel<<<dim3(DDIM / 64, DDIM / 64), 256, 0, stream>>>(W_d, Wt_d, DDIM, DDIM);
    gemm_kernel<0><<<dim3(4, 4), 256, 0, stream>>>(
        W_dim, DDIM, nullptr, 0, W_fus + DDIM * DDIM, zeros512, W_comb2, DDIM);
    bcomb_kernel<<<dim3(2), 256, 0, stream>>>(b_dim, W_fus + DDIM * DDIM, b_fus, b_comb);
    wsplit_kernel<<<dim3(DDIM / 64, DDIM / 64), 256, 0, stream>>>(W_comb2, Wt_comb2, DDIM, DDIM);

    // comb = src @ Wf1 + b_comb + neigh @ W_comb2   -> out, then BN1
    gemm_split_nt<0, 0, DDIM><<<dim3(DDIM / 128, N_ROWS / 128), 256, 0, stream>>>(
        src, Wt_fus1, b_comb, nullptr, out, DDIM);
    gemm_split_nt<1, 0, DDIM><<<dim3(DDIM / 128, N_ROWS / 128), 256, 0, stream>>>(
        bufA, Wt_comb2, nullptr, out, out, DDIM);
    bn_stats_kernel<<<dim3(DDIM / 64, 16), 256, 0, stream>>>(out, sums1);
    bn_apply_kernel<0><<<dim3(8192), 256, 0, stream>>>(out, out, sums1, g1, bt1, invN);

    // encoder, chunked: h = tanh(comb@We1+b1); t = h@We2 + b2 + comb
    for (int r0 = 0; r0 < N_ROWS; r0 += CHUNK) {
        gemm_split_nt<0, 1, DDIM><<<dim3(FDIM / 128, CHUNK / 128), 256, 0, stream>>>(
            out + (size_t)r0 * DDIM, Wt_e1, b_e1, nullptr, hbuf, FDIM);
        gemm_split_nt<1, 0, FDIM><<<dim3(DDIM / 128, CHUNK / 128), 256, 0, stream>>>(
            hbuf, Wt_e2, b_e2, out + (size_t)r0 * DDIM, bufA + (size_t)r0 * DDIM,
            DDIM);
    }
    bn_stats_kernel<<<dim3(DDIM / 64, 16), 256, 0, stream>>>(bufA, sums2);
    bn_apply_kernel<0><<<dim3(8192), 256, 0, stream>>>(bufA, bufA, sums2, g2, bt2, invN);

    // decoder -> out, BN3 + tanh
    gemm_split_nt<0, 0, DDIM><<<dim3(DDIM / 128, N_ROWS / 128), 256, 0, stream>>>(
        bufA, Wt_d, b_d, nullptr, out, DDIM);
    bn_stats_kernel<<<dim3(DDIM / 64, 16), 256, 0, stream>>>(out, sums3);
    bn_apply_kernel<1><<<dim3(8192), 256, 0, stream>>>(out, out, sums3, g_d, bt_d, invN);
}